// Round 12
// baseline (149.543 us; speedup 1.0000x reference)
//
#include <hip/hip_runtime.h>
#include <stdint.h>

#define HID 2560
#define NH 80
#define PDIM 64
#define NDIM 128
#define INTER 5120
#define CONV_DIM 5376
#define PROJ_DIM 10576
#define NBATCH 64
#define EPS_ 1e-5f

typedef short short8 __attribute__((ext_vector_type(8)));
typedef float f32x4 __attribute__((ext_vector_type(4)));

__device__ __forceinline__ unsigned short f2bf(float f){
  unsigned u = __builtin_bit_cast(unsigned, f);
  u += 0x7FFFu + ((u >> 16) & 1u);
  return (unsigned short)(u >> 16);
}
__device__ __forceinline__ float silu_(float x){ return x / (1.f + __expf(-x)); }

// ---------------- K_dt: exact f32 dt partials + X->bf16 conversion ----------------
__global__ __launch_bounds__(256) void k_dt(const float* __restrict__ X,
                                            const float* __restrict__ W,
                                            float* __restrict__ dt_part,
                                            unsigned short* __restrict__ Xb){
  const int h = blockIdx.x, ks = blockIdx.y;
  const int tid = threadIdx.x, wid = tid >> 6, lane = tid & 63;
  const float* wr = W + (size_t)(INTER + CONV_DIM + h) * HID + ks * 320;
  float w[5];
  #pragma unroll
  for (int i = 0; i < 5; ++i) w[i] = wr[lane + i * 64];
  #pragma unroll
  for (int bi = 0; bi < 16; ++bi){
    const int b = wid * 16 + bi;
    const float* xr = X + (size_t)b * HID + ks * 320;
    float x[5];
    float acc = 0.f;
    #pragma unroll
    for (int i = 0; i < 5; ++i){ x[i] = xr[lane + i * 64]; acc += x[i] * w[i]; }
    if (h == 0){
      #pragma unroll
      for (int i = 0; i < 5; ++i)
        Xb[(size_t)b * HID + ks * 320 + lane + i * 64] = f2bf(x[i]);
    }
    #pragma unroll
    for (int m = 32; m; m >>= 1) acc += __shfl_xor(acc, m);
    if (lane == 0) dt_part[(ks * NBATCH + b) * NH + h] = acc;
  }
}

// ---------------- K1: proj partials, 16-col tiles, K-split 16 (high TLP) ----------------
// grid (661,16) = 10576 single-wave blocks (~32 waves/CU). 5 iters/wave.
// PROBE: body repeated 4x, store acc*0.25 (surfaces in rocprof top-5 with counters).
__global__ __launch_bounds__(64) void k1_proj(const unsigned short* __restrict__ Xb,
                                              const float* __restrict__ W,
                                              float* __restrict__ pp){
  const int lane = threadIdx.x;
  const int lr = lane & 15, lg = lane >> 4;
  const int n0 = blockIdx.x * 16;
  const int ks = blockIdx.y;
  const int kb = ks * 160;
  const short* ap = (const short*)Xb + (size_t)lr * HID + kb + lg * 8;
  const float* bp = W + (size_t)(n0 + lr) * HID + kb + lg * 8;
  f32x4 acc0 = {0,0,0,0}, acc1 = {0,0,0,0}, acc2 = {0,0,0,0}, acc3 = {0,0,0,0};
  for (int rep = 0; rep < 4; ++rep){
    #pragma unroll
    for (int s = 0; s < 5; ++s){
      const int k = s * 32;
      short8 a0 = *(const short8*)(ap + k);
      short8 a1 = *(const short8*)(ap + 16 * HID + k);
      short8 a2 = *(const short8*)(ap + 32 * HID + k);
      short8 a3 = *(const short8*)(ap + 48 * HID + k);
      float4 b0 = *(const float4*)(bp + k);
      float4 b1 = *(const float4*)(bp + k + 4);
      short8 bb;
      bb[0] = (short)f2bf(b0.x); bb[1] = (short)f2bf(b0.y);
      bb[2] = (short)f2bf(b0.z); bb[3] = (short)f2bf(b0.w);
      bb[4] = (short)f2bf(b1.x); bb[5] = (short)f2bf(b1.y);
      bb[6] = (short)f2bf(b1.z); bb[7] = (short)f2bf(b1.w);
      acc0 = __builtin_amdgcn_mfma_f32_16x16x32_bf16(a0, bb, acc0, 0, 0, 0);
      acc1 = __builtin_amdgcn_mfma_f32_16x16x32_bf16(a1, bb, acc1, 0, 0, 0);
      acc2 = __builtin_amdgcn_mfma_f32_16x16x32_bf16(a2, bb, acc2, 0, 0, 0);
      acc3 = __builtin_amdgcn_mfma_f32_16x16x32_bf16(a3, bb, acc3, 0, 0, 0);
    }
  }
  float* plane = pp + (size_t)ks * NBATCH * PROJ_DIM;
  #pragma unroll
  for (int r = 0; r < 4; ++r){
    const int m = lg * 4 + r;
    plane[(size_t)(m     ) * PROJ_DIM + n0 + lr] = acc0[r] * 0.25f;
    plane[(size_t)(m + 16) * PROJ_DIM + n0 + lr] = acc1[r] * 0.25f;
    plane[(size_t)(m + 32) * PROJ_DIM + n0 + lr] = acc2[r] * 0.25f;
    plane[(size_t)(m + 48) * PROJ_DIM + n0 + lr] = acc3[r] * 0.25f;
  }
}

// ---------------- K2a: conv+silu (pp 16-plane sum); dt finalize; B·C ----------------
__global__ __launch_bounds__(256) void k2a(const float* __restrict__ cs,
                                           const float* __restrict__ cw,
                                           const float* __restrict__ cb,
                                           const float* __restrict__ pp,
                                           const float* __restrict__ dt_part,
                                           const float* __restrict__ dt_bias,
                                           const float* __restrict__ A_log,
                                           float* __restrict__ hs_bc,
                                           float* __restrict__ dt_sp,
                                           float* __restrict__ dAv,
                                           float* __restrict__ s_bc){
  const int b = blockIdx.y;
  const int c0 = blockIdx.x * 384;
  const int tid = threadIdx.x;
  const size_t plane = (size_t)NBATCH * PROJ_DIM;
  __shared__ float bc[384];
  for (int i = tid; i < 384; i += 256){
    const int c = c0 + i;
    float4 s4 = *(const float4*)(cs + ((size_t)b * CONV_DIM + c) * 4);
    float4 w4 = *(const float4*)(cw + (size_t)c * 4);
    const size_t pidx = (size_t)b * PROJ_DIM + INTER + c;
    float hbc = 0.f;
    #pragma unroll
    for (int ks = 0; ks < 16; ++ks) hbc += pp[(size_t)ks * plane + pidx];
    float x = s4.y * w4.x + s4.z * w4.y + s4.w * w4.z + hbc * w4.w + cb[c];
    float v = silu_(x);
    hs_bc[(size_t)b * CONV_DIM + c] = v;
    if (blockIdx.x == 13) bc[i] = v;
  }
  if (blockIdx.x == 0 && tid < NH){
    float acc = dt_bias[tid];
    #pragma unroll
    for (int ks = 0; ks < 8; ++ks) acc += dt_part[(ks * NBATCH + b) * NH + tid];
    float sp = acc > 15.f ? acc : log1pf(__expf(acc));
    sp = fminf(fmaxf(sp, 0.f), 100.f);
    dt_sp[b * NH + tid] = sp;
    dAv[b * NH + tid] = __expf(-sp * __expf(A_log[tid]));
  }
  if (blockIdx.x == 13){
    __syncthreads();
    if (tid < 64){
      float p = bc[128 + tid] * bc[256 + tid] + bc[192 + tid] * bc[320 + tid];
      #pragma unroll
      for (int m = 32; m; m >>= 1) p += __shfl_xor(p, m);
      if (tid == 0) s_bc[b] = p;
    }
  }
}

// ---------------- K2b: SSM step, gate (pp 16-plane sum), yf + sumsq partials ----------------
__global__ __launch_bounds__(256) void k2b(const float* __restrict__ ssm,
                                           const float* __restrict__ hs_bc,
                                           const float* __restrict__ pp,
                                           const float* __restrict__ dt_sp,
                                           const float* __restrict__ dAv,
                                           const float* __restrict__ s_bc,
                                           const float* __restrict__ Dp,
                                           const float* __restrict__ norm_w,
                                           unsigned short* __restrict__ yfb,
                                           float* __restrict__ ssq_part){
  const int h = blockIdx.x, b = blockIdx.y;
  const int tid = threadIdx.x;
  const int wid = tid >> 6, lane = tid & 63;
  const int lr = lane & 15, lg = lane >> 4;
  const float dA_s = dAv[b * NH + h];
  const float coef = dt_sp[b * NH + h] * s_bc[b] + Dp[h];
  const size_t plane = (size_t)NBATCH * PROJ_DIM;
  const float* Cb = hs_bc + (size_t)b * CONV_DIM + INTER + NDIM;
  float4 c0 = *(const float4*)(Cb + lr * 8);
  float4 c1 = *(const float4*)(Cb + lr * 8 + 4);
  const float* srow = ssm + ((size_t)b * NH + h) * PDIM * NDIM;
  float ssq = 0.f;
  __shared__ float ssql[4];
  #pragma unroll
  for (int r = 0; r < 4; ++r){
    const int p = wid * 16 + r * 4 + lg;
    const float* sp_ = srow + (size_t)p * NDIM + lr * 8;
    float4 v0 = *(const float4*)(sp_);
    float4 v1 = *(const float4*)(sp_ + 4);
    float dot = v0.x*c0.x + v0.y*c0.y + v0.z*c0.z + v0.w*c0.w
              + v1.x*c1.x + v1.y*c1.y + v1.z*c1.z + v1.w*c1.w;
    dot += __shfl_xor(dot, 1); dot += __shfl_xor(dot, 2);
    dot += __shfl_xor(dot, 4); dot += __shfl_xor(dot, 8);
    if (lr == 0){
      const int hp = h * PDIM + p;
      float hs = hs_bc[(size_t)b * CONV_DIM + hp];
      float y = dA_s * dot + hs * coef;
      const size_t gi = (size_t)b * PROJ_DIM + hp;
      float g = 0.f;
      #pragma unroll
      for (int ks = 0; ks < 16; ++ks) g += pp[(size_t)ks * plane + gi];
      float yf = y * silu_(g) * norm_w[hp];
      yfb[(size_t)b * INTER + hp] = f2bf(yf);
      ssq += yf * yf;
    }
  }
  #pragma unroll
  for (int m = 32; m; m >>= 1) ssq += __shfl_xor(ssq, m);
  if (lane == 0) ssql[wid] = ssq;
  __syncthreads();
  if (tid == 0) ssq_part[b * NH + h] = ssql[0] + ssql[1] + ssql[2] + ssql[3];
}

// ---------------- K3: out partials, 16-col tiles, K-split 16 (high TLP) ----------------
__global__ __launch_bounds__(64) void k3_out(const unsigned short* __restrict__ Yb,
                                             const float* __restrict__ W,
                                             float* __restrict__ part){
  const int lane = threadIdx.x;
  const int lr = lane & 15, lg = lane >> 4;
  const int n0 = blockIdx.x * 16;
  const int ks = blockIdx.y;
  const int kb = ks * 320;
  const short* ap = (const short*)Yb + (size_t)lr * INTER + kb + lg * 8;
  const float* bp = W + (size_t)(n0 + lr) * INTER + kb + lg * 8;
  f32x4 acc0 = {0,0,0,0}, acc1 = {0,0,0,0}, acc2 = {0,0,0,0}, acc3 = {0,0,0,0};
  #pragma unroll
  for (int s = 0; s < 10; ++s){
    const int k = s * 32;
    short8 a0 = *(const short8*)(ap + k);
    short8 a1 = *(const short8*)(ap + 16 * INTER + k);
    short8 a2 = *(const short8*)(ap + 32 * INTER + k);
    short8 a3 = *(const short8*)(ap + 48 * INTER + k);
    float4 b0 = *(const float4*)(bp + k);
    float4 b1 = *(const float4*)(bp + k + 4);
    short8 bb;
    bb[0] = (short)f2bf(b0.x); bb[1] = (short)f2bf(b0.y);
    bb[2] = (short)f2bf(b0.z); bb[3] = (short)f2bf(b0.w);
    bb[4] = (short)f2bf(b1.x); bb[5] = (short)f2bf(b1.y);
    bb[6] = (short)f2bf(b1.z); bb[7] = (short)f2bf(b1.w);
    acc0 = __builtin_amdgcn_mfma_f32_16x16x32_bf16(a0, bb, acc0, 0, 0, 0);
    acc1 = __builtin_amdgcn_mfma_f32_16x16x32_bf16(a1, bb, acc1, 0, 0, 0);
    acc2 = __builtin_amdgcn_mfma_f32_16x16x32_bf16(a2, bb, acc2, 0, 0, 0);
    acc3 = __builtin_amdgcn_mfma_f32_16x16x32_bf16(a3, bb, acc3, 0, 0, 0);
  }
  float* pt = part + (size_t)ks * NBATCH * 2560;
  #pragma unroll
  for (int r = 0; r < 4; ++r){
    const int m = lg * 4 + r;
    pt[(size_t)(m     ) * 2560 + n0 + lr] = acc0[r];
    pt[(size_t)(m + 16) * 2560 + n0 + lr] = acc1[r];
    pt[(size_t)(m + 32) * 2560 + n0 + lr] = acc2[r];
    pt[(size_t)(m + 48) * 2560 + n0 + lr] = acc3[r];
  }
}

// ---------------- K4: reduce 16 K-partials, apply rsqrt(mean(yf^2)+eps) ----------------
__global__ __launch_bounds__(256) void k4_norm(const float* __restrict__ part,
                                               const float* __restrict__ ssq_part,
                                               float* __restrict__ out){
  const int b = blockIdx.y;
  const int tid = threadIdx.x;
  __shared__ float w4[4];
  __shared__ float sc;
  float v = (tid < NH) ? ssq_part[b * NH + tid] : 0.f;
  #pragma unroll
  for (int m = 32; m; m >>= 1) v += __shfl_xor(v, m);
  const int wid = tid >> 6, lane = tid & 63;
  if (lane == 0) w4[wid] = v;
  __syncthreads();
  if (tid == 0){
    float total = w4[0] + w4[1] + w4[2] + w4[3];
    sc = rsqrtf(total / (float)INTER + EPS_);
  }
  __syncthreads();
  const int j = blockIdx.x * 256 + tid;
  const size_t idx = (size_t)b * 2560 + j;
  const size_t plane = (size_t)NBATCH * 2560;
  float s = 0.f;
  #pragma unroll
  for (int ks = 0; ks < 16; ++ks) s += part[(size_t)ks * plane + idx];
  out[idx] = sc * s;
}

extern "C" void kernel_launch(void* const* d_in, const int* in_sizes, int n_in,
                              void* d_out, int out_size, void* d_ws, size_t ws_size,
                              hipStream_t stream){
  const float* x_in       = (const float*)d_in[0];
  const float* conv_state = (const float*)d_in[1];
  const float* ssm_state  = (const float*)d_in[2];
  const float* in_proj_w  = (const float*)d_in[3];
  const float* conv_w     = (const float*)d_in[4];
  const float* conv_b     = (const float*)d_in[5];
  const float* dt_bias    = (const float*)d_in[6];
  const float* A_log      = (const float*)d_in[7];
  const float* Dp         = (const float*)d_in[8];
  const float* norm_w     = (const float*)d_in[9];
  const float* out_proj_w = (const float*)d_in[10];
  float* out = (float*)d_out;

  char* ws = (char*)d_ws;
  unsigned short* Xb   = (unsigned short*)(ws);             // 327,680 B
  float* dt_part       = (float*)(ws + 327680);             // 163,840 B
  float* pp            = (float*)(ws + 491520);             // 43,319,296 B (16 proj planes)
  float* hs_bc         = (float*)(ws + 43810816);           // 1,376,256 B
  float* dt_sp         = (float*)(ws + 45187072);           // 20,480 B
  float* dAv           = (float*)(ws + 45207552);           // 20,480 B
  float* s_bc          = (float*)(ws + 45228032);           // 256 B
  float* ssq           = (float*)(ws + 45228288);           // 20,480 B
  unsigned short* Yb   = (unsigned short*)(ws + 45248768);  // 655,360 B
  float* part          = (float*)(ws + 45904128);           // 10,485,760 B (16 out planes)

  k_dt<<<dim3(NH, 8), dim3(256), 0, stream>>>(x_in, in_proj_w, dt_part, Xb);
  k1_proj<<<dim3(661, 16), dim3(64), 0, stream>>>(Xb, in_proj_w, pp);
  k2a<<<dim3(14, NBATCH), dim3(256), 0, stream>>>(conv_state, conv_w, conv_b, pp,
                                                  dt_part, dt_bias, A_log,
                                                  hs_bc, dt_sp, dAv, s_bc);
  k2b<<<dim3(NH, NBATCH), dim3(256), 0, stream>>>(ssm_state, hs_bc, pp, dt_sp, dAv,
                                                  s_bc, Dp, norm_w, Yb, ssq);
  k3_out<<<dim3(160, 16), dim3(64), 0, stream>>>(Yb, out_proj_w, part);
  k4_norm<<<dim3(10, NBATCH), dim3(256), 0, stream>>>(part, ssq, out);
}

// Round 13
// 147.576 us; speedup vs baseline: 1.0133x; 1.0133x over previous
//
#include <hip/hip_runtime.h>
#include <stdint.h>

#define HID 2560
#define NH 80
#define PDIM 64
#define NDIM 128
#define INTER 5120
#define CONV_DIM 5376
#define PROJ_DIM 10576
#define NBATCH 64
#define EPS_ 1e-5f

typedef short short8 __attribute__((ext_vector_type(8)));
typedef float f32x4 __attribute__((ext_vector_type(4)));

__device__ __forceinline__ unsigned short f2bf(float f){
  unsigned u = __builtin_bit_cast(unsigned, f);
  u += 0x7FFFu + ((u >> 16) & 1u);
  return (unsigned short)(u >> 16);
}
__device__ __forceinline__ float silu_(float x){ return x / (1.f + __expf(-x)); }

// ---------------- K_dt: exact f32 dt partials + X->bf16 conversion ----------------
__global__ __launch_bounds__(256) void k_dt(const float* __restrict__ X,
                                            const float* __restrict__ W,
                                            float* __restrict__ dt_part,
                                            unsigned short* __restrict__ Xb){
  const int h = blockIdx.x, ks = blockIdx.y;
  const int tid = threadIdx.x, wid = tid >> 6, lane = tid & 63;
  const float* wr = W + (size_t)(INTER + CONV_DIM + h) * HID + ks * 320;
  float w[5];
  #pragma unroll
  for (int i = 0; i < 5; ++i) w[i] = wr[lane + i * 64];
  #pragma unroll
  for (int bi = 0; bi < 16; ++bi){
    const int b = wid * 16 + bi;
    const float* xr = X + (size_t)b * HID + ks * 320;
    float x[5];
    float acc = 0.f;
    #pragma unroll
    for (int i = 0; i < 5; ++i){ x[i] = xr[lane + i * 64]; acc += x[i] * w[i]; }
    if (h == 0){
      #pragma unroll
      for (int i = 0; i < 5; ++i)
        Xb[(size_t)b * HID + ks * 320 + lane + i * 64] = f2bf(x[i]);
    }
    #pragma unroll
    for (int m = 32; m; m >>= 1) acc += __shfl_xor(acc, m);
    if (lane == 0) dt_part[(ks * NBATCH + b) * NH + h] = acc;
  }
}

// ---------------- K1: proj partials, 16-col tiles, K-split 8 (high TLP, clean) ----------------
// grid (661,8) = 5288 single-wave blocks (~20 waves/CU). 10 iters/wave.
__global__ __launch_bounds__(64) void k1_proj(const unsigned short* __restrict__ Xb,
                                              const float* __restrict__ W,
                                              float* __restrict__ pp){
  const int lane = threadIdx.x;
  const int lr = lane & 15, lg = lane >> 4;
  const int n0 = blockIdx.x * 16;
  const int ks = blockIdx.y;
  const int kb = ks * 320;
  const short* ap = (const short*)Xb + (size_t)lr * HID + kb + lg * 8;
  const float* bp = W + (size_t)(n0 + lr) * HID + kb + lg * 8;
  f32x4 acc0 = {0,0,0,0}, acc1 = {0,0,0,0}, acc2 = {0,0,0,0}, acc3 = {0,0,0,0};
  #pragma unroll
  for (int s = 0; s < 10; ++s){
    const int k = s * 32;
    short8 a0 = *(const short8*)(ap + k);
    short8 a1 = *(const short8*)(ap + 16 * HID + k);
    short8 a2 = *(const short8*)(ap + 32 * HID + k);
    short8 a3 = *(const short8*)(ap + 48 * HID + k);
    float4 b0 = *(const float4*)(bp + k);
    float4 b1 = *(const float4*)(bp + k + 4);
    short8 bb;
    bb[0] = (short)f2bf(b0.x); bb[1] = (short)f2bf(b0.y);
    bb[2] = (short)f2bf(b0.z); bb[3] = (short)f2bf(b0.w);
    bb[4] = (short)f2bf(b1.x); bb[5] = (short)f2bf(b1.y);
    bb[6] = (short)f2bf(b1.z); bb[7] = (short)f2bf(b1.w);
    acc0 = __builtin_amdgcn_mfma_f32_16x16x32_bf16(a0, bb, acc0, 0, 0, 0);
    acc1 = __builtin_amdgcn_mfma_f32_16x16x32_bf16(a1, bb, acc1, 0, 0, 0);
    acc2 = __builtin_amdgcn_mfma_f32_16x16x32_bf16(a2, bb, acc2, 0, 0, 0);
    acc3 = __builtin_amdgcn_mfma_f32_16x16x32_bf16(a3, bb, acc3, 0, 0, 0);
  }
  float* plane = pp + (size_t)ks * NBATCH * PROJ_DIM;
  #pragma unroll
  for (int r = 0; r < 4; ++r){
    const int m = lg * 4 + r;
    plane[(size_t)(m     ) * PROJ_DIM + n0 + lr] = acc0[r];
    plane[(size_t)(m + 16) * PROJ_DIM + n0 + lr] = acc1[r];
    plane[(size_t)(m + 32) * PROJ_DIM + n0 + lr] = acc2[r];
    plane[(size_t)(m + 48) * PROJ_DIM + n0 + lr] = acc3[r];
  }
}

// ---------------- K2a: conv+silu (pp 8-plane sum); dt finalize; B·C ----------------
__global__ __launch_bounds__(256) void k2a(const float* __restrict__ cs,
                                           const float* __restrict__ cw,
                                           const float* __restrict__ cb,
                                           const float* __restrict__ pp,
                                           const float* __restrict__ dt_part,
                                           const float* __restrict__ dt_bias,
                                           const float* __restrict__ A_log,
                                           float* __restrict__ hs_bc,
                                           float* __restrict__ dt_sp,
                                           float* __restrict__ dAv,
                                           float* __restrict__ s_bc){
  const int b = blockIdx.y;
  const int c0 = blockIdx.x * 384;
  const int tid = threadIdx.x;
  const size_t plane = (size_t)NBATCH * PROJ_DIM;
  __shared__ float bc[384];
  for (int i = tid; i < 384; i += 256){
    const int c = c0 + i;
    float4 s4 = *(const float4*)(cs + ((size_t)b * CONV_DIM + c) * 4);
    float4 w4 = *(const float4*)(cw + (size_t)c * 4);
    const size_t pidx = (size_t)b * PROJ_DIM + INTER + c;
    float hbc = 0.f;
    #pragma unroll
    for (int ks = 0; ks < 8; ++ks) hbc += pp[(size_t)ks * plane + pidx];
    float x = s4.y * w4.x + s4.z * w4.y + s4.w * w4.z + hbc * w4.w + cb[c];
    float v = silu_(x);
    hs_bc[(size_t)b * CONV_DIM + c] = v;
    if (blockIdx.x == 13) bc[i] = v;
  }
  if (blockIdx.x == 0 && tid < NH){
    float acc = dt_bias[tid];
    #pragma unroll
    for (int ks = 0; ks < 8; ++ks) acc += dt_part[(ks * NBATCH + b) * NH + tid];
    float sp = acc > 15.f ? acc : log1pf(__expf(acc));
    sp = fminf(fmaxf(sp, 0.f), 100.f);
    dt_sp[b * NH + tid] = sp;
    dAv[b * NH + tid] = __expf(-sp * __expf(A_log[tid]));
  }
  if (blockIdx.x == 13){
    __syncthreads();
    if (tid < 64){
      float p = bc[128 + tid] * bc[256 + tid] + bc[192 + tid] * bc[320 + tid];
      #pragma unroll
      for (int m = 32; m; m >>= 1) p += __shfl_xor(p, m);
      if (tid == 0) s_bc[b] = p;
    }
  }
}

// ---------------- K2b: SSM step, gate (pp 8-plane sum), yf + sumsq partials ----------------
__global__ __launch_bounds__(256) void k2b(const float* __restrict__ ssm,
                                           const float* __restrict__ hs_bc,
                                           const float* __restrict__ pp,
                                           const float* __restrict__ dt_sp,
                                           const float* __restrict__ dAv,
                                           const float* __restrict__ s_bc,
                                           const float* __restrict__ Dp,
                                           const float* __restrict__ norm_w,
                                           unsigned short* __restrict__ yfb,
                                           float* __restrict__ ssq_part){
  const int h = blockIdx.x, b = blockIdx.y;
  const int tid = threadIdx.x;
  const int wid = tid >> 6, lane = tid & 63;
  const int lr = lane & 15, lg = lane >> 4;
  const float dA_s = dAv[b * NH + h];
  const float coef = dt_sp[b * NH + h] * s_bc[b] + Dp[h];
  const size_t plane = (size_t)NBATCH * PROJ_DIM;
  const float* Cb = hs_bc + (size_t)b * CONV_DIM + INTER + NDIM;
  float4 c0 = *(const float4*)(Cb + lr * 8);
  float4 c1 = *(const float4*)(Cb + lr * 8 + 4);
  const float* srow = ssm + ((size_t)b * NH + h) * PDIM * NDIM;
  float ssq = 0.f;
  __shared__ float ssql[4];
  #pragma unroll
  for (int r = 0; r < 4; ++r){
    const int p = wid * 16 + r * 4 + lg;
    const float* sp_ = srow + (size_t)p * NDIM + lr * 8;
    float4 v0 = *(const float4*)(sp_);
    float4 v1 = *(const float4*)(sp_ + 4);
    float dot = v0.x*c0.x + v0.y*c0.y + v0.z*c0.z + v0.w*c0.w
              + v1.x*c1.x + v1.y*c1.y + v1.z*c1.z + v1.w*c1.w;
    dot += __shfl_xor(dot, 1); dot += __shfl_xor(dot, 2);
    dot += __shfl_xor(dot, 4); dot += __shfl_xor(dot, 8);
    if (lr == 0){
      const int hp = h * PDIM + p;
      float hs = hs_bc[(size_t)b * CONV_DIM + hp];
      float y = dA_s * dot + hs * coef;
      const size_t gi = (size_t)b * PROJ_DIM + hp;
      float g = 0.f;
      #pragma unroll
      for (int ks = 0; ks < 8; ++ks) g += pp[(size_t)ks * plane + gi];
      float yf = y * silu_(g) * norm_w[hp];
      yfb[(size_t)b * INTER + hp] = f2bf(yf);
      ssq += yf * yf;
    }
  }
  #pragma unroll
  for (int m = 32; m; m >>= 1) ssq += __shfl_xor(ssq, m);
  if (lane == 0) ssql[wid] = ssq;
  __syncthreads();
  if (tid == 0) ssq_part[b * NH + h] = ssql[0] + ssql[1] + ssql[2] + ssql[3];
}

// ---------------- K3: out partials, 16-col tiles, K-split 16 (high TLP) ----------------
__global__ __launch_bounds__(64) void k3_out(const unsigned short* __restrict__ Yb,
                                             const float* __restrict__ W,
                                             float* __restrict__ part){
  const int lane = threadIdx.x;
  const int lr = lane & 15, lg = lane >> 4;
  const int n0 = blockIdx.x * 16;
  const int ks = blockIdx.y;
  const int kb = ks * 320;
  const short* ap = (const short*)Yb + (size_t)lr * INTER + kb + lg * 8;
  const float* bp = W + (size_t)(n0 + lr) * INTER + kb + lg * 8;
  f32x4 acc0 = {0,0,0,0}, acc1 = {0,0,0,0}, acc2 = {0,0,0,0}, acc3 = {0,0,0,0};
  #pragma unroll
  for (int s = 0; s < 10; ++s){
    const int k = s * 32;
    short8 a0 = *(const short8*)(ap + k);
    short8 a1 = *(const short8*)(ap + 16 * INTER + k);
    short8 a2 = *(const short8*)(ap + 32 * INTER + k);
    short8 a3 = *(const short8*)(ap + 48 * INTER + k);
    float4 b0 = *(const float4*)(bp + k);
    float4 b1 = *(const float4*)(bp + k + 4);
    short8 bb;
    bb[0] = (short)f2bf(b0.x); bb[1] = (short)f2bf(b0.y);
    bb[2] = (short)f2bf(b0.z); bb[3] = (short)f2bf(b0.w);
    bb[4] = (short)f2bf(b1.x); bb[5] = (short)f2bf(b1.y);
    bb[6] = (short)f2bf(b1.z); bb[7] = (short)f2bf(b1.w);
    acc0 = __builtin_amdgcn_mfma_f32_16x16x32_bf16(a0, bb, acc0, 0, 0, 0);
    acc1 = __builtin_amdgcn_mfma_f32_16x16x32_bf16(a1, bb, acc1, 0, 0, 0);
    acc2 = __builtin_amdgcn_mfma_f32_16x16x32_bf16(a2, bb, acc2, 0, 0, 0);
    acc3 = __builtin_amdgcn_mfma_f32_16x16x32_bf16(a3, bb, acc3, 0, 0, 0);
  }
  float* pt = part + (size_t)ks * NBATCH * 2560;
  #pragma unroll
  for (int r = 0; r < 4; ++r){
    const int m = lg * 4 + r;
    pt[(size_t)(m     ) * 2560 + n0 + lr] = acc0[r];
    pt[(size_t)(m + 16) * 2560 + n0 + lr] = acc1[r];
    pt[(size_t)(m + 32) * 2560 + n0 + lr] = acc2[r];
    pt[(size_t)(m + 48) * 2560 + n0 + lr] = acc3[r];
  }
}

// ---------------- K4: reduce 16 K-partials, apply rsqrt(mean(yf^2)+eps) ----------------
__global__ __launch_bounds__(256) void k4_norm(const float* __restrict__ part,
                                               const float* __restrict__ ssq_part,
                                               float* __restrict__ out){
  const int b = blockIdx.y;
  const int tid = threadIdx.x;
  __shared__ float w4[4];
  __shared__ float sc;
  float v = (tid < NH) ? ssq_part[b * NH + tid] : 0.f;
  #pragma unroll
  for (int m = 32; m; m >>= 1) v += __shfl_xor(v, m);
  const int wid = tid >> 6, lane = tid & 63;
  if (lane == 0) w4[wid] = v;
  __syncthreads();
  if (tid == 0){
    float total = w4[0] + w4[1] + w4[2] + w4[3];
    sc = rsqrtf(total / (float)INTER + EPS_);
  }
  __syncthreads();
  const int j = blockIdx.x * 256 + tid;
  const size_t idx = (size_t)b * 2560 + j;
  const size_t plane = (size_t)NBATCH * 2560;
  float s = 0.f;
  #pragma unroll
  for (int ks = 0; ks < 16; ++ks) s += part[(size_t)ks * plane + idx];
  out[idx] = sc * s;
}

extern "C" void kernel_launch(void* const* d_in, const int* in_sizes, int n_in,
                              void* d_out, int out_size, void* d_ws, size_t ws_size,
                              hipStream_t stream){
  const float* x_in       = (const float*)d_in[0];
  const float* conv_state = (const float*)d_in[1];
  const float* ssm_state  = (const float*)d_in[2];
  const float* in_proj_w  = (const float*)d_in[3];
  const float* conv_w     = (const float*)d_in[4];
  const float* conv_b     = (const float*)d_in[5];
  const float* dt_bias    = (const float*)d_in[6];
  const float* A_log      = (const float*)d_in[7];
  const float* Dp         = (const float*)d_in[8];
  const float* norm_w     = (const float*)d_in[9];
  const float* out_proj_w = (const float*)d_in[10];
  float* out = (float*)d_out;

  char* ws = (char*)d_ws;
  unsigned short* Xb   = (unsigned short*)(ws);             // 327,680 B
  float* dt_part       = (float*)(ws + 327680);             // 163,840 B
  float* pp            = (float*)(ws + 491520);             // 21,659,648 B (8 proj planes)
  float* hs_bc         = (float*)(ws + 22151168);           // 1,376,256 B
  float* dt_sp         = (float*)(ws + 23527424);           // 20,480 B
  float* dAv           = (float*)(ws + 23547904);           // 20,480 B
  float* s_bc          = (float*)(ws + 23568384);           // 256 B
  float* ssq           = (float*)(ws + 23568640);           // 20,480 B
  unsigned short* Yb   = (unsigned short*)(ws + 23589120);  // 655,360 B
  float* part          = (float*)(ws + 24244480);           // 10,485,760 B (16 out planes)

  k_dt<<<dim3(NH, 8), dim3(256), 0, stream>>>(x_in, in_proj_w, dt_part, Xb);
  k1_proj<<<dim3(661, 8), dim3(64), 0, stream>>>(Xb, in_proj_w, pp);
  k2a<<<dim3(14, NBATCH), dim3(256), 0, stream>>>(conv_state, conv_w, conv_b, pp,
                                                  dt_part, dt_bias, A_log,
                                                  hs_bc, dt_sp, dAv, s_bc);
  k2b<<<dim3(NH, NBATCH), dim3(256), 0, stream>>>(ssm_state, hs_bc, pp, dt_sp, dAv,
                                                  s_bc, Dp, norm_w, Yb, ssq);
  k3_out<<<dim3(160, 16), dim3(64), 0, stream>>>(Yb, out_proj_w, part);
  k4_norm<<<dim3(10, NBATCH), dim3(256), 0, stream>>>(part, ssq, out);
}

// Round 14
// 134.636 us; speedup vs baseline: 1.1107x; 1.0961x over previous
//
#include <hip/hip_runtime.h>
#include <stdint.h>

#define HID 2560
#define NH 80
#define PDIM 64
#define NDIM 128
#define INTER 5120
#define CONV_DIM 5376
#define PROJ_DIM 10576
#define NBATCH 64
#define EPS_ 1e-5f

typedef short short8 __attribute__((ext_vector_type(8)));
typedef float f32x4 __attribute__((ext_vector_type(4)));

__device__ __forceinline__ unsigned short f2bf(float f){
  unsigned u = __builtin_bit_cast(unsigned, f);
  u += 0x7FFFu + ((u >> 16) & 1u);
  return (unsigned short)(u >> 16);
}
__device__ __forceinline__ float silu_(float x){ return x / (1.f + __expf(-x)); }

// ---------------- K_dt: exact f32 dt partials + X->bf16 conversion ----------------
__global__ __launch_bounds__(256) void k_dt(const float* __restrict__ X,
                                            const float* __restrict__ W,
                                            float* __restrict__ dt_part,
                                            unsigned short* __restrict__ Xb){
  const int h = blockIdx.x, ks = blockIdx.y;
  const int tid = threadIdx.x, wid = tid >> 6, lane = tid & 63;
  const float* wr = W + (size_t)(INTER + CONV_DIM + h) * HID + ks * 320;
  float w[5];
  #pragma unroll
  for (int i = 0; i < 5; ++i) w[i] = wr[lane + i * 64];
  #pragma unroll
  for (int bi = 0; bi < 16; ++bi){
    const int b = wid * 16 + bi;
    const float* xr = X + (size_t)b * HID + ks * 320;
    float x[5];
    float acc = 0.f;
    #pragma unroll
    for (int i = 0; i < 5; ++i){ x[i] = xr[lane + i * 64]; acc += x[i] * w[i]; }
    if (h == 0){
      #pragma unroll
      for (int i = 0; i < 5; ++i)
        Xb[(size_t)b * HID + ks * 320 + lane + i * 64] = f2bf(x[i]);
    }
    #pragma unroll
    for (int m = 32; m; m >>= 1) acc += __shfl_xor(acc, m);
    if (lane == 0) dt_part[(ks * NBATCH + b) * NH + h] = acc;
  }
}

// ---------------- K1: proj partials, 16-col tiles, K-split 4, 4-stage prefetch ring ----------------
// grid (661,4) = 2644 single-wave blocks (~10 waves/CU), 20 iters/wave.
__global__ __launch_bounds__(64, 1) void k1_proj(const unsigned short* __restrict__ Xb,
                                                 const float* __restrict__ W,
                                                 float* __restrict__ pp){
  const int lane = threadIdx.x;
  const int lr = lane & 15, lg = lane >> 4;
  const int n0 = blockIdx.x * 16;
  const int ks = blockIdx.y;
  const int kb = ks * 640;
  const short* ap = (const short*)Xb + (size_t)lr * HID + kb + lg * 8;
  const float* bp = W + (size_t)(n0 + lr) * HID + kb + lg * 8;
  f32x4 acc0 = {0,0,0,0}, acc1 = {0,0,0,0}, acc2 = {0,0,0,0}, acc3 = {0,0,0,0};
  short8 A0[4], A1[4], A2[4], A3[4];
  float4 B0[4], B1[4];
  #pragma unroll
  for (int p = 0; p < 4; ++p){
    const int k = p * 32;
    A0[p] = *(const short8*)(ap + k);
    A1[p] = *(const short8*)(ap + 16 * HID + k);
    A2[p] = *(const short8*)(ap + 32 * HID + k);
    A3[p] = *(const short8*)(ap + 48 * HID + k);
    B0[p] = *(const float4*)(bp + k);
    B1[p] = *(const float4*)(bp + k + 4);
  }
  #pragma unroll 4
  for (int s = 0; s < 16; ++s){
    const int p = s & 3;
    short8 bb;
    bb[0]=(short)f2bf(B0[p].x); bb[1]=(short)f2bf(B0[p].y);
    bb[2]=(short)f2bf(B0[p].z); bb[3]=(short)f2bf(B0[p].w);
    bb[4]=(short)f2bf(B1[p].x); bb[5]=(short)f2bf(B1[p].y);
    bb[6]=(short)f2bf(B1[p].z); bb[7]=(short)f2bf(B1[p].w);
    acc0 = __builtin_amdgcn_mfma_f32_16x16x32_bf16(A0[p], bb, acc0, 0, 0, 0);
    acc1 = __builtin_amdgcn_mfma_f32_16x16x32_bf16(A1[p], bb, acc1, 0, 0, 0);
    acc2 = __builtin_amdgcn_mfma_f32_16x16x32_bf16(A2[p], bb, acc2, 0, 0, 0);
    acc3 = __builtin_amdgcn_mfma_f32_16x16x32_bf16(A3[p], bb, acc3, 0, 0, 0);
    const int k = (s + 4) * 32;
    A0[p] = *(const short8*)(ap + k);
    A1[p] = *(const short8*)(ap + 16 * HID + k);
    A2[p] = *(const short8*)(ap + 32 * HID + k);
    A3[p] = *(const short8*)(ap + 48 * HID + k);
    B0[p] = *(const float4*)(bp + k);
    B1[p] = *(const float4*)(bp + k + 4);
  }
  #pragma unroll
  for (int s = 16; s < 20; ++s){
    const int p = s & 3;
    short8 bb;
    bb[0]=(short)f2bf(B0[p].x); bb[1]=(short)f2bf(B0[p].y);
    bb[2]=(short)f2bf(B0[p].z); bb[3]=(short)f2bf(B0[p].w);
    bb[4]=(short)f2bf(B1[p].x); bb[5]=(short)f2bf(B1[p].y);
    bb[6]=(short)f2bf(B1[p].z); bb[7]=(short)f2bf(B1[p].w);
    acc0 = __builtin_amdgcn_mfma_f32_16x16x32_bf16(A0[p], bb, acc0, 0, 0, 0);
    acc1 = __builtin_amdgcn_mfma_f32_16x16x32_bf16(A1[p], bb, acc1, 0, 0, 0);
    acc2 = __builtin_amdgcn_mfma_f32_16x16x32_bf16(A2[p], bb, acc2, 0, 0, 0);
    acc3 = __builtin_amdgcn_mfma_f32_16x16x32_bf16(A3[p], bb, acc3, 0, 0, 0);
  }
  float* plane = pp + (size_t)ks * NBATCH * PROJ_DIM;
  #pragma unroll
  for (int r = 0; r < 4; ++r){
    const int m = lg * 4 + r;
    plane[(size_t)(m     ) * PROJ_DIM + n0 + lr] = acc0[r];
    plane[(size_t)(m + 16) * PROJ_DIM + n0 + lr] = acc1[r];
    plane[(size_t)(m + 32) * PROJ_DIM + n0 + lr] = acc2[r];
    plane[(size_t)(m + 48) * PROJ_DIM + n0 + lr] = acc3[r];
  }
}

// ---------------- K2a: conv+silu (pp 4-plane sum); dt finalize; B·C ----------------
__global__ __launch_bounds__(256) void k2a(const float* __restrict__ cs,
                                           const float* __restrict__ cw,
                                           const float* __restrict__ cb,
                                           const float* __restrict__ pp,
                                           const float* __restrict__ dt_part,
                                           const float* __restrict__ dt_bias,
                                           const float* __restrict__ A_log,
                                           float* __restrict__ hs_bc,
                                           float* __restrict__ dt_sp,
                                           float* __restrict__ dAv,
                                           float* __restrict__ s_bc){
  const int b = blockIdx.y;
  const int c0 = blockIdx.x * 384;
  const int tid = threadIdx.x;
  const size_t plane = (size_t)NBATCH * PROJ_DIM;
  __shared__ float bc[384];
  for (int i = tid; i < 384; i += 256){
    const int c = c0 + i;
    float4 s4 = *(const float4*)(cs + ((size_t)b * CONV_DIM + c) * 4);
    float4 w4 = *(const float4*)(cw + (size_t)c * 4);
    const size_t pidx = (size_t)b * PROJ_DIM + INTER + c;
    float hbc = pp[pidx] + pp[plane + pidx] + pp[2*plane + pidx] + pp[3*plane + pidx];
    float x = s4.y * w4.x + s4.z * w4.y + s4.w * w4.z + hbc * w4.w + cb[c];
    float v = silu_(x);
    hs_bc[(size_t)b * CONV_DIM + c] = v;
    if (blockIdx.x == 13) bc[i] = v;
  }
  if (blockIdx.x == 0 && tid < NH){
    float acc = dt_bias[tid];
    #pragma unroll
    for (int ks = 0; ks < 8; ++ks) acc += dt_part[(ks * NBATCH + b) * NH + tid];
    float sp = acc > 15.f ? acc : log1pf(__expf(acc));
    sp = fminf(fmaxf(sp, 0.f), 100.f);
    dt_sp[b * NH + tid] = sp;
    dAv[b * NH + tid] = __expf(-sp * __expf(A_log[tid]));
  }
  if (blockIdx.x == 13){
    __syncthreads();
    if (tid < 64){
      float p = bc[128 + tid] * bc[256 + tid] + bc[192 + tid] * bc[320 + tid];
      #pragma unroll
      for (int m = 32; m; m >>= 1) p += __shfl_xor(p, m);
      if (tid == 0) s_bc[b] = p;
    }
  }
}

// ---------------- K2b: SSM step, gate (pp 4-plane sum), yf + sumsq partials ----------------
__global__ __launch_bounds__(256) void k2b(const float* __restrict__ ssm,
                                           const float* __restrict__ hs_bc,
                                           const float* __restrict__ pp,
                                           const float* __restrict__ dt_sp,
                                           const float* __restrict__ dAv,
                                           const float* __restrict__ s_bc,
                                           const float* __restrict__ Dp,
                                           const float* __restrict__ norm_w,
                                           unsigned short* __restrict__ yfb,
                                           float* __restrict__ ssq_part){
  const int h = blockIdx.x, b = blockIdx.y;
  const int tid = threadIdx.x;
  const int wid = tid >> 6, lane = tid & 63;
  const int lr = lane & 15, lg = lane >> 4;
  const float dA_s = dAv[b * NH + h];
  const float coef = dt_sp[b * NH + h] * s_bc[b] + Dp[h];
  const size_t plane = (size_t)NBATCH * PROJ_DIM;
  const float* Cb = hs_bc + (size_t)b * CONV_DIM + INTER + NDIM;
  float4 c0 = *(const float4*)(Cb + lr * 8);
  float4 c1 = *(const float4*)(Cb + lr * 8 + 4);
  const float* srow = ssm + ((size_t)b * NH + h) * PDIM * NDIM;
  float ssq = 0.f;
  __shared__ float ssql[4];
  #pragma unroll
  for (int r = 0; r < 4; ++r){
    const int p = wid * 16 + r * 4 + lg;
    const float* sp_ = srow + (size_t)p * NDIM + lr * 8;
    float4 v0 = *(const float4*)(sp_);
    float4 v1 = *(const float4*)(sp_ + 4);
    float dot = v0.x*c0.x + v0.y*c0.y + v0.z*c0.z + v0.w*c0.w
              + v1.x*c1.x + v1.y*c1.y + v1.z*c1.z + v1.w*c1.w;
    dot += __shfl_xor(dot, 1); dot += __shfl_xor(dot, 2);
    dot += __shfl_xor(dot, 4); dot += __shfl_xor(dot, 8);
    if (lr == 0){
      const int hp = h * PDIM + p;
      float hs = hs_bc[(size_t)b * CONV_DIM + hp];
      float y = dA_s * dot + hs * coef;
      const size_t gi = (size_t)b * PROJ_DIM + hp;
      float g = pp[gi] + pp[plane + gi] + pp[2*plane + gi] + pp[3*plane + gi];
      float yf = y * silu_(g) * norm_w[hp];
      yfb[(size_t)b * INTER + hp] = f2bf(yf);
      ssq += yf * yf;
    }
  }
  #pragma unroll
  for (int m = 32; m; m >>= 1) ssq += __shfl_xor(ssq, m);
  if (lane == 0) ssql[wid] = ssq;
  __syncthreads();
  if (tid == 0) ssq_part[b * NH + h] = ssql[0] + ssql[1] + ssql[2] + ssql[3];
}

// ---------------- K3: out partials = yf_bf16 @ W_out^T — K-split 4, prefetch ring ----------------
__global__ __launch_bounds__(64, 1) void k3_out(const unsigned short* __restrict__ Yb,
                                                const float* __restrict__ W,
                                                float* __restrict__ part){
  const int lane = threadIdx.x;
  const int lr = lane & 15, lg = lane >> 4;
  const int n0 = blockIdx.x * 16;
  const int ks = blockIdx.y;
  const int kb = ks * 1280;
  const short* ap = (const short*)Yb + (size_t)lr * INTER + kb + lg * 8;
  const float* bp = W + (size_t)(n0 + lr) * INTER + kb + lg * 8;
  f32x4 acc0 = {0,0,0,0}, acc1 = {0,0,0,0}, acc2 = {0,0,0,0}, acc3 = {0,0,0,0};
  short8 A0[4], A1[4], A2[4], A3[4];
  float4 B0[4], B1[4];
  #pragma unroll
  for (int p = 0; p < 4; ++p){
    const int k = p * 32;
    A0[p] = *(const short8*)(ap + k);
    A1[p] = *(const short8*)(ap + 16 * INTER + k);
    A2[p] = *(const short8*)(ap + 32 * INTER + k);
    A3[p] = *(const short8*)(ap + 48 * INTER + k);
    B0[p] = *(const float4*)(bp + k);
    B1[p] = *(const float4*)(bp + k + 4);
  }
  #pragma unroll 4
  for (int s = 0; s < 36; ++s){
    const int p = s & 3;
    short8 bb;
    bb[0]=(short)f2bf(B0[p].x); bb[1]=(short)f2bf(B0[p].y);
    bb[2]=(short)f2bf(B0[p].z); bb[3]=(short)f2bf(B0[p].w);
    bb[4]=(short)f2bf(B1[p].x); bb[5]=(short)f2bf(B1[p].y);
    bb[6]=(short)f2bf(B1[p].z); bb[7]=(short)f2bf(B1[p].w);
    acc0 = __builtin_amdgcn_mfma_f32_16x16x32_bf16(A0[p], bb, acc0, 0, 0, 0);
    acc1 = __builtin_amdgcn_mfma_f32_16x16x32_bf16(A1[p], bb, acc1, 0, 0, 0);
    acc2 = __builtin_amdgcn_mfma_f32_16x16x32_bf16(A2[p], bb, acc2, 0, 0, 0);
    acc3 = __builtin_amdgcn_mfma_f32_16x16x32_bf16(A3[p], bb, acc3, 0, 0, 0);
    const int k = (s + 4) * 32;
    A0[p] = *(const short8*)(ap + k);
    A1[p] = *(const short8*)(ap + 16 * INTER + k);
    A2[p] = *(const short8*)(ap + 32 * INTER + k);
    A3[p] = *(const short8*)(ap + 48 * INTER + k);
    B0[p] = *(const float4*)(bp + k);
    B1[p] = *(const float4*)(bp + k + 4);
  }
  #pragma unroll
  for (int s = 36; s < 40; ++s){
    const int p = s & 3;
    short8 bb;
    bb[0]=(short)f2bf(B0[p].x); bb[1]=(short)f2bf(B0[p].y);
    bb[2]=(short)f2bf(B0[p].z); bb[3]=(short)f2bf(B0[p].w);
    bb[4]=(short)f2bf(B1[p].x); bb[5]=(short)f2bf(B1[p].y);
    bb[6]=(short)f2bf(B1[p].z); bb[7]=(short)f2bf(B1[p].w);
    acc0 = __builtin_amdgcn_mfma_f32_16x16x32_bf16(A0[p], bb, acc0, 0, 0, 0);
    acc1 = __builtin_amdgcn_mfma_f32_16x16x32_bf16(A1[p], bb, acc1, 0, 0, 0);
    acc2 = __builtin_amdgcn_mfma_f32_16x16x32_bf16(A2[p], bb, acc2, 0, 0, 0);
    acc3 = __builtin_amdgcn_mfma_f32_16x16x32_bf16(A3[p], bb, acc3, 0, 0, 0);
  }
  float* pt = part + (size_t)ks * NBATCH * 2560;
  #pragma unroll
  for (int r = 0; r < 4; ++r){
    const int m = lg * 4 + r;
    pt[(size_t)(m     ) * 2560 + n0 + lr] = acc0[r];
    pt[(size_t)(m + 16) * 2560 + n0 + lr] = acc1[r];
    pt[(size_t)(m + 32) * 2560 + n0 + lr] = acc2[r];
    pt[(size_t)(m + 48) * 2560 + n0 + lr] = acc3[r];
  }
}

// ---------------- K4: reduce 4 K-partials, apply rsqrt(mean(yf^2)+eps) ----------------
__global__ __launch_bounds__(256) void k4_norm(const float* __restrict__ part,
                                               const float* __restrict__ ssq_part,
                                               float* __restrict__ out){
  const int b = blockIdx.y;
  const int tid = threadIdx.x;
  __shared__ float w4[4];
  __shared__ float sc;
  float v = (tid < NH) ? ssq_part[b * NH + tid] : 0.f;
  #pragma unroll
  for (int m = 32; m; m >>= 1) v += __shfl_xor(v, m);
  const int wid = tid >> 6, lane = tid & 63;
  if (lane == 0) w4[wid] = v;
  __syncthreads();
  if (tid == 0){
    float total = w4[0] + w4[1] + w4[2] + w4[3];
    sc = rsqrtf(total / (float)INTER + EPS_);
  }
  __syncthreads();
  const int j = blockIdx.x * 256 + tid;
  const size_t idx = (size_t)b * 2560 + j;
  const size_t plane = (size_t)NBATCH * 2560;
  float s = part[idx] + part[plane + idx] + part[2*plane + idx] + part[3*plane + idx];
  out[idx] = sc * s;
}

extern "C" void kernel_launch(void* const* d_in, const int* in_sizes, int n_in,
                              void* d_out, int out_size, void* d_ws, size_t ws_size,
                              hipStream_t stream){
  const float* x_in       = (const float*)d_in[0];
  const float* conv_state = (const float*)d_in[1];
  const float* ssm_state  = (const float*)d_in[2];
  const float* in_proj_w  = (const float*)d_in[3];
  const float* conv_w     = (const float*)d_in[4];
  const float* conv_b     = (const float*)d_in[5];
  const float* dt_bias    = (const float*)d_in[6];
  const float* A_log      = (const float*)d_in[7];
  const float* Dp         = (const float*)d_in[8];
  const float* norm_w     = (const float*)d_in[9];
  const float* out_proj_w = (const float*)d_in[10];
  float* out = (float*)d_out;

  char* ws = (char*)d_ws;
  unsigned short* Xb   = (unsigned short*)(ws);             // 327,680 B
  float* dt_part       = (float*)(ws + 327680);             // 163,840 B
  float* pp            = (float*)(ws + 491520);             // 10,829,824 B (4 proj planes)
  float* hs_bc         = (float*)(ws + 11321344);           // 1,376,256 B
  float* dt_sp         = (float*)(ws + 12697600);           // 20,480 B
  float* dAv           = (float*)(ws + 12718080);           // 20,480 B
  float* s_bc          = (float*)(ws + 12738560);           // 256 B
  float* ssq           = (float*)(ws + 12738816);           // 20,480 B
  unsigned short* Yb   = (unsigned short*)(ws + 12759296);  // 655,360 B
  float* part          = (float*)(ws + 13414656);           // 2,621,440 B (4 out planes)

  k_dt<<<dim3(NH, 8), dim3(256), 0, stream>>>(x_in, in_proj_w, dt_part, Xb);
  k1_proj<<<dim3(661, 4), dim3(64), 0, stream>>>(Xb, in_proj_w, pp);
  k2a<<<dim3(14, NBATCH), dim3(256), 0, stream>>>(conv_state, conv_w, conv_b, pp,
                                                  dt_part, dt_bias, A_log,
                                                  hs_bc, dt_sp, dAv, s_bc);
  k2b<<<dim3(NH, NBATCH), dim3(256), 0, stream>>>(ssm_state, hs_bc, pp, dt_sp, dAv,
                                                  s_bc, Dp, norm_w, Yb, ssq);
  k3_out<<<dim3(160, 4), dim3(64), 0, stream>>>(Yb, out_proj_w, part);
  k4_norm<<<dim3(10, NBATCH), dim3(256), 0, stream>>>(part, ssq, out);
}

// Round 15
// 127.471 us; speedup vs baseline: 1.1732x; 1.0562x over previous
//
#include <hip/hip_runtime.h>
#include <stdint.h>

#define HID 2560
#define NH 80
#define PDIM 64
#define NDIM 128
#define INTER 5120
#define CONV_DIM 5376
#define PROJ_DIM 10576
#define NBATCH 64
#define EPS_ 1e-5f

typedef short short8 __attribute__((ext_vector_type(8)));
typedef float f32x4 __attribute__((ext_vector_type(4)));

__device__ __forceinline__ unsigned short f2bf(float f){
  unsigned u = __builtin_bit_cast(unsigned, f);
  u += 0x7FFFu + ((u >> 16) & 1u);
  return (unsigned short)(u >> 16);
}
__device__ __forceinline__ float silu_(float x){ return x / (1.f + __expf(-x)); }

// ---------------- K_dt: exact f32 dt partials + X->bf16 conversion ----------------
__global__ __launch_bounds__(256) void k_dt(const float* __restrict__ X,
                                            const float* __restrict__ W,
                                            float* __restrict__ dt_part,
                                            unsigned short* __restrict__ Xb){
  const int h = blockIdx.x, ks = blockIdx.y;
  const int tid = threadIdx.x, wid = tid >> 6, lane = tid & 63;
  const float* wr = W + (size_t)(INTER + CONV_DIM + h) * HID + ks * 320;
  float w[5];
  #pragma unroll
  for (int i = 0; i < 5; ++i) w[i] = wr[lane + i * 64];
  #pragma unroll
  for (int bi = 0; bi < 16; ++bi){
    const int b = wid * 16 + bi;
    const float* xr = X + (size_t)b * HID + ks * 320;
    float x[5];
    float acc = 0.f;
    #pragma unroll
    for (int i = 0; i < 5; ++i){ x[i] = xr[lane + i * 64]; acc += x[i] * w[i]; }
    if (h == 0){
      #pragma unroll
      for (int i = 0; i < 5; ++i)
        Xb[(size_t)b * HID + ks * 320 + lane + i * 64] = f2bf(x[i]);
    }
    #pragma unroll
    for (int m = 32; m; m >>= 1) acc += __shfl_xor(acc, m);
    if (lane == 0) dt_part[(ks * NBATCH + b) * NH + h] = acc;
  }
}

// ---------------- K1: proj partials, N-tile 64/wave (A shared x4), K-split 8 ----------------
// grid (166,8) = 1328 single-wave blocks. Every A-load feeds 4 N-subtiles:
// CU-side bytes: A 54 MB + B 108 MB (vs 216+108 at N-16). 2-deep ring, fully unrolled.
__global__ __launch_bounds__(64, 1) void k1_proj(const unsigned short* __restrict__ Xb,
                                                 const float* __restrict__ W,
                                                 float* __restrict__ pp){
  const int lane = threadIdx.x;
  const int lr = lane & 15, lg = lane >> 4;
  const int n0 = blockIdx.x * 64;
  const int ks = blockIdx.y;
  const int kb = ks * 320;
  const short* ap = (const short*)Xb + (size_t)lr * HID + kb + lg * 8;
  const float* bp0; const float* bp1; const float* bp2; const float* bp3;
  {
    int r0 = n0;          if (r0 > PROJ_DIM - 16) r0 = PROJ_DIM - 16;
    int r1 = n0 + 16;     if (r1 > PROJ_DIM - 16) r1 = PROJ_DIM - 16;
    int r2 = n0 + 32;     if (r2 > PROJ_DIM - 16) r2 = PROJ_DIM - 16;
    int r3 = n0 + 48;     if (r3 > PROJ_DIM - 16) r3 = PROJ_DIM - 16;
    bp0 = W + (size_t)(r0 + lr) * HID + kb + lg * 8;
    bp1 = W + (size_t)(r1 + lr) * HID + kb + lg * 8;
    bp2 = W + (size_t)(r2 + lr) * HID + kb + lg * 8;
    bp3 = W + (size_t)(r3 + lr) * HID + kb + lg * 8;
  }
  f32x4 acc0[4], acc1[4], acc2[4], acc3[4];   // [mt] per nt
  #pragma unroll
  for (int mt = 0; mt < 4; ++mt){
    acc0[mt] = (f32x4){0,0,0,0}; acc1[mt] = (f32x4){0,0,0,0};
    acc2[mt] = (f32x4){0,0,0,0}; acc3[mt] = (f32x4){0,0,0,0};
  }
  short8 A0[2], A1[2], A2[2], A3[2];
  float4 Bv0[2][2], Bv1[2][2], Bv2[2][2], Bv3[2][2]; // [stage][half]
  // prologue: stage 0
  A0[0] = *(const short8*)(ap);
  A1[0] = *(const short8*)(ap + 16 * HID);
  A2[0] = *(const short8*)(ap + 32 * HID);
  A3[0] = *(const short8*)(ap + 48 * HID);
  Bv0[0][0] = *(const float4*)(bp0); Bv0[0][1] = *(const float4*)(bp0 + 4);
  Bv1[0][0] = *(const float4*)(bp1); Bv1[0][1] = *(const float4*)(bp1 + 4);
  Bv2[0][0] = *(const float4*)(bp2); Bv2[0][1] = *(const float4*)(bp2 + 4);
  Bv3[0][0] = *(const float4*)(bp3); Bv3[0][1] = *(const float4*)(bp3 + 4);
  #pragma unroll
  for (int s = 0; s < 10; ++s){
    const int p = s & 1;
    if (s + 1 < 10){
      const int k = (s + 1) * 32, q = p ^ 1;
      A0[q] = *(const short8*)(ap + k);
      A1[q] = *(const short8*)(ap + 16 * HID + k);
      A2[q] = *(const short8*)(ap + 32 * HID + k);
      A3[q] = *(const short8*)(ap + 48 * HID + k);
      Bv0[q][0] = *(const float4*)(bp0 + k); Bv0[q][1] = *(const float4*)(bp0 + k + 4);
      Bv1[q][0] = *(const float4*)(bp1 + k); Bv1[q][1] = *(const float4*)(bp1 + k + 4);
      Bv2[q][0] = *(const float4*)(bp2 + k); Bv2[q][1] = *(const float4*)(bp2 + k + 4);
      Bv3[q][0] = *(const float4*)(bp3 + k); Bv3[q][1] = *(const float4*)(bp3 + k + 4);
    }
    short8 bb0, bb1, bb2, bb3;
    bb0[0]=(short)f2bf(Bv0[p][0].x); bb0[1]=(short)f2bf(Bv0[p][0].y);
    bb0[2]=(short)f2bf(Bv0[p][0].z); bb0[3]=(short)f2bf(Bv0[p][0].w);
    bb0[4]=(short)f2bf(Bv0[p][1].x); bb0[5]=(short)f2bf(Bv0[p][1].y);
    bb0[6]=(short)f2bf(Bv0[p][1].z); bb0[7]=(short)f2bf(Bv0[p][1].w);
    bb1[0]=(short)f2bf(Bv1[p][0].x); bb1[1]=(short)f2bf(Bv1[p][0].y);
    bb1[2]=(short)f2bf(Bv1[p][0].z); bb1[3]=(short)f2bf(Bv1[p][0].w);
    bb1[4]=(short)f2bf(Bv1[p][1].x); bb1[5]=(short)f2bf(Bv1[p][1].y);
    bb1[6]=(short)f2bf(Bv1[p][1].z); bb1[7]=(short)f2bf(Bv1[p][1].w);
    bb2[0]=(short)f2bf(Bv2[p][0].x); bb2[1]=(short)f2bf(Bv2[p][0].y);
    bb2[2]=(short)f2bf(Bv2[p][0].z); bb2[3]=(short)f2bf(Bv2[p][0].w);
    bb2[4]=(short)f2bf(Bv2[p][1].x); bb2[5]=(short)f2bf(Bv2[p][1].y);
    bb2[6]=(short)f2bf(Bv2[p][1].z); bb2[7]=(short)f2bf(Bv2[p][1].w);
    bb3[0]=(short)f2bf(Bv3[p][0].x); bb3[1]=(short)f2bf(Bv3[p][0].y);
    bb3[2]=(short)f2bf(Bv3[p][0].z); bb3[3]=(short)f2bf(Bv3[p][0].w);
    bb3[4]=(short)f2bf(Bv3[p][1].x); bb3[5]=(short)f2bf(Bv3[p][1].y);
    bb3[6]=(short)f2bf(Bv3[p][1].z); bb3[7]=(short)f2bf(Bv3[p][1].w);
    acc0[0] = __builtin_amdgcn_mfma_f32_16x16x32_bf16(A0[p], bb0, acc0[0], 0, 0, 0);
    acc0[1] = __builtin_amdgcn_mfma_f32_16x16x32_bf16(A1[p], bb0, acc0[1], 0, 0, 0);
    acc0[2] = __builtin_amdgcn_mfma_f32_16x16x32_bf16(A2[p], bb0, acc0[2], 0, 0, 0);
    acc0[3] = __builtin_amdgcn_mfma_f32_16x16x32_bf16(A3[p], bb0, acc0[3], 0, 0, 0);
    acc1[0] = __builtin_amdgcn_mfma_f32_16x16x32_bf16(A0[p], bb1, acc1[0], 0, 0, 0);
    acc1[1] = __builtin_amdgcn_mfma_f32_16x16x32_bf16(A1[p], bb1, acc1[1], 0, 0, 0);
    acc1[2] = __builtin_amdgcn_mfma_f32_16x16x32_bf16(A2[p], bb1, acc1[2], 0, 0, 0);
    acc1[3] = __builtin_amdgcn_mfma_f32_16x16x32_bf16(A3[p], bb1, acc1[3], 0, 0, 0);
    acc2[0] = __builtin_amdgcn_mfma_f32_16x16x32_bf16(A0[p], bb2, acc2[0], 0, 0, 0);
    acc2[1] = __builtin_amdgcn_mfma_f32_16x16x32_bf16(A1[p], bb2, acc2[1], 0, 0, 0);
    acc2[2] = __builtin_amdgcn_mfma_f32_16x16x32_bf16(A2[p], bb2, acc2[2], 0, 0, 0);
    acc2[3] = __builtin_amdgcn_mfma_f32_16x16x32_bf16(A3[p], bb2, acc2[3], 0, 0, 0);
    acc3[0] = __builtin_amdgcn_mfma_f32_16x16x32_bf16(A0[p], bb3, acc3[0], 0, 0, 0);
    acc3[1] = __builtin_amdgcn_mfma_f32_16x16x32_bf16(A1[p], bb3, acc3[1], 0, 0, 0);
    acc3[2] = __builtin_amdgcn_mfma_f32_16x16x32_bf16(A2[p], bb3, acc3[2], 0, 0, 0);
    acc3[3] = __builtin_amdgcn_mfma_f32_16x16x32_bf16(A3[p], bb3, acc3[3], 0, 0, 0);
  }
  float* plane = pp + (size_t)ks * NBATCH * PROJ_DIM;
  #pragma unroll
  for (int mt = 0; mt < 4; ++mt){
    #pragma unroll
    for (int r = 0; r < 4; ++r){
      const int m = mt * 16 + lg * 4 + r;
      float* pm = plane + (size_t)m * PROJ_DIM;
      if (n0      < PROJ_DIM) pm[n0      + lr] = acc0[mt][r];
      if (n0 + 16 < PROJ_DIM) pm[n0 + 16 + lr] = acc1[mt][r];
      if (n0 + 32 < PROJ_DIM) pm[n0 + 32 + lr] = acc2[mt][r];
      if (n0 + 48 < PROJ_DIM) pm[n0 + 48 + lr] = acc3[mt][r];
    }
  }
}

// ---------------- K2a: conv+silu (pp 8-plane sum); dt finalize; B·C ----------------
__global__ __launch_bounds__(256) void k2a(const float* __restrict__ cs,
                                           const float* __restrict__ cw,
                                           const float* __restrict__ cb,
                                           const float* __restrict__ pp,
                                           const float* __restrict__ dt_part,
                                           const float* __restrict__ dt_bias,
                                           const float* __restrict__ A_log,
                                           float* __restrict__ hs_bc,
                                           float* __restrict__ dt_sp,
                                           float* __restrict__ dAv,
                                           float* __restrict__ s_bc){
  const int b = blockIdx.y;
  const int c0 = blockIdx.x * 384;
  const int tid = threadIdx.x;
  const size_t plane = (size_t)NBATCH * PROJ_DIM;
  __shared__ float bc[384];
  for (int i = tid; i < 384; i += 256){
    const int c = c0 + i;
    float4 s4 = *(const float4*)(cs + ((size_t)b * CONV_DIM + c) * 4);
    float4 w4 = *(const float4*)(cw + (size_t)c * 4);
    const size_t pidx = (size_t)b * PROJ_DIM + INTER + c;
    float hbc = 0.f;
    #pragma unroll
    for (int ks = 0; ks < 8; ++ks) hbc += pp[(size_t)ks * plane + pidx];
    float x = s4.y * w4.x + s4.z * w4.y + s4.w * w4.z + hbc * w4.w + cb[c];
    float v = silu_(x);
    hs_bc[(size_t)b * CONV_DIM + c] = v;
    if (blockIdx.x == 13) bc[i] = v;
  }
  if (blockIdx.x == 0 && tid < NH){
    float acc = dt_bias[tid];
    #pragma unroll
    for (int ks = 0; ks < 8; ++ks) acc += dt_part[(ks * NBATCH + b) * NH + tid];
    float sp = acc > 15.f ? acc : log1pf(__expf(acc));
    sp = fminf(fmaxf(sp, 0.f), 100.f);
    dt_sp[b * NH + tid] = sp;
    dAv[b * NH + tid] = __expf(-sp * __expf(A_log[tid]));
  }
  if (blockIdx.x == 13){
    __syncthreads();
    if (tid < 64){
      float p = bc[128 + tid] * bc[256 + tid] + bc[192 + tid] * bc[320 + tid];
      #pragma unroll
      for (int m = 32; m; m >>= 1) p += __shfl_xor(p, m);
      if (tid == 0) s_bc[b] = p;
    }
  }
}

// ---------------- K2b: SSM step, gate (pp 8-plane sum), yf + sumsq partials ----------------
__global__ __launch_bounds__(256) void k2b(const float* __restrict__ ssm,
                                           const float* __restrict__ hs_bc,
                                           const float* __restrict__ pp,
                                           const float* __restrict__ dt_sp,
                                           const float* __restrict__ dAv,
                                           const float* __restrict__ s_bc,
                                           const float* __restrict__ Dp,
                                           const float* __restrict__ norm_w,
                                           unsigned short* __restrict__ yfb,
                                           float* __restrict__ ssq_part){
  const int h = blockIdx.x, b = blockIdx.y;
  const int tid = threadIdx.x;
  const int wid = tid >> 6, lane = tid & 63;
  const int lr = lane & 15, lg = lane >> 4;
  const float dA_s = dAv[b * NH + h];
  const float coef = dt_sp[b * NH + h] * s_bc[b] + Dp[h];
  const size_t plane = (size_t)NBATCH * PROJ_DIM;
  const float* Cb = hs_bc + (size_t)b * CONV_DIM + INTER + NDIM;
  float4 c0 = *(const float4*)(Cb + lr * 8);
  float4 c1 = *(const float4*)(Cb + lr * 8 + 4);
  const float* srow = ssm + ((size_t)b * NH + h) * PDIM * NDIM;
  float ssq = 0.f;
  __shared__ float ssql[4];
  #pragma unroll
  for (int r = 0; r < 4; ++r){
    const int p = wid * 16 + r * 4 + lg;
    const float* sp_ = srow + (size_t)p * NDIM + lr * 8;
    float4 v0 = *(const float4*)(sp_);
    float4 v1 = *(const float4*)(sp_ + 4);
    float dot = v0.x*c0.x + v0.y*c0.y + v0.z*c0.z + v0.w*c0.w
              + v1.x*c1.x + v1.y*c1.y + v1.z*c1.z + v1.w*c1.w;
    dot += __shfl_xor(dot, 1); dot += __shfl_xor(dot, 2);
    dot += __shfl_xor(dot, 4); dot += __shfl_xor(dot, 8);
    if (lr == 0){
      const int hp = h * PDIM + p;
      float hs = hs_bc[(size_t)b * CONV_DIM + hp];
      float y = dA_s * dot + hs * coef;
      const size_t gi = (size_t)b * PROJ_DIM + hp;
      float g = 0.f;
      #pragma unroll
      for (int ks = 0; ks < 8; ++ks) g += pp[(size_t)ks * plane + gi];
      float yf = y * silu_(g) * norm_w[hp];
      yfb[(size_t)b * INTER + hp] = f2bf(yf);
      ssq += yf * yf;
    }
  }
  #pragma unroll
  for (int m = 32; m; m >>= 1) ssq += __shfl_xor(ssq, m);
  if (lane == 0) ssql[wid] = ssq;
  __syncthreads();
  if (tid == 0) ssq_part[b * NH + h] = ssql[0] + ssql[1] + ssql[2] + ssql[3];
}

// ---------------- K3: out partials = yf_bf16 @ W_out^T — K-split 4, prefetch ring ----------------
__global__ __launch_bounds__(64, 1) void k3_out(const unsigned short* __restrict__ Yb,
                                                const float* __restrict__ W,
                                                float* __restrict__ part){
  const int lane = threadIdx.x;
  const int lr = lane & 15, lg = lane >> 4;
  const int n0 = blockIdx.x * 16;
  const int ks = blockIdx.y;
  const int kb = ks * 1280;
  const short* ap = (const short*)Yb + (size_t)lr * INTER + kb + lg * 8;
  const float* bp = W + (size_t)(n0 + lr) * INTER + kb + lg * 8;
  f32x4 acc0 = {0,0,0,0}, acc1 = {0,0,0,0}, acc2 = {0,0,0,0}, acc3 = {0,0,0,0};
  short8 A0[4], A1[4], A2[4], A3[4];
  float4 B0[4], B1[4];
  #pragma unroll
  for (int p = 0; p < 4; ++p){
    const int k = p * 32;
    A0[p] = *(const short8*)(ap + k);
    A1[p] = *(const short8*)(ap + 16 * INTER + k);
    A2[p] = *(const short8*)(ap + 32 * INTER + k);
    A3[p] = *(const short8*)(ap + 48 * INTER + k);
    B0[p] = *(const float4*)(bp + k);
    B1[p] = *(const float4*)(bp + k + 4);
  }
  #pragma unroll 4
  for (int s = 0; s < 36; ++s){
    const int p = s & 3;
    short8 bb;
    bb[0]=(short)f2bf(B0[p].x); bb[1]=(short)f2bf(B0[p].y);
    bb[2]=(short)f2bf(B0[p].z); bb[3]=(short)f2bf(B0[p].w);
    bb[4]=(short)f2bf(B1[p].x); bb[5]=(short)f2bf(B1[p].y);
    bb[6]=(short)f2bf(B1[p].z); bb[7]=(short)f2bf(B1[p].w);
    acc0 = __builtin_amdgcn_mfma_f32_16x16x32_bf16(A0[p], bb, acc0, 0, 0, 0);
    acc1 = __builtin_amdgcn_mfma_f32_16x16x32_bf16(A1[p], bb, acc1, 0, 0, 0);
    acc2 = __builtin_amdgcn_mfma_f32_16x16x32_bf16(A2[p], bb, acc2, 0, 0, 0);
    acc3 = __builtin_amdgcn_mfma_f32_16x16x32_bf16(A3[p], bb, acc3, 0, 0, 0);
    const int k = (s + 4) * 32;
    A0[p] = *(const short8*)(ap + k);
    A1[p] = *(const short8*)(ap + 16 * INTER + k);
    A2[p] = *(const short8*)(ap + 32 * INTER + k);
    A3[p] = *(const short8*)(ap + 48 * INTER + k);
    B0[p] = *(const float4*)(bp + k);
    B1[p] = *(const float4*)(bp + k + 4);
  }
  #pragma unroll
  for (int s = 36; s < 40; ++s){
    const int p = s & 3;
    short8 bb;
    bb[0]=(short)f2bf(B0[p].x); bb[1]=(short)f2bf(B0[p].y);
    bb[2]=(short)f2bf(B0[p].z); bb[3]=(short)f2bf(B0[p].w);
    bb[4]=(short)f2bf(B1[p].x); bb[5]=(short)f2bf(B1[p].y);
    bb[6]=(short)f2bf(B1[p].z); bb[7]=(short)f2bf(B1[p].w);
    acc0 = __builtin_amdgcn_mfma_f32_16x16x32_bf16(A0[p], bb, acc0, 0, 0, 0);
    acc1 = __builtin_amdgcn_mfma_f32_16x16x32_bf16(A1[p], bb, acc1, 0, 0, 0);
    acc2 = __builtin_amdgcn_mfma_f32_16x16x32_bf16(A2[p], bb, acc2, 0, 0, 0);
    acc3 = __builtin_amdgcn_mfma_f32_16x16x32_bf16(A3[p], bb, acc3, 0, 0, 0);
  }
  float* pt = part + (size_t)ks * NBATCH * 2560;
  #pragma unroll
  for (int r = 0; r < 4; ++r){
    const int m = lg * 4 + r;
    pt[(size_t)(m     ) * 2560 + n0 + lr] = acc0[r];
    pt[(size_t)(m + 16) * 2560 + n0 + lr] = acc1[r];
    pt[(size_t)(m + 32) * 2560 + n0 + lr] = acc2[r];
    pt[(size_t)(m + 48) * 2560 + n0 + lr] = acc3[r];
  }
}

// ---------------- K4: reduce 4 K-partials, apply rsqrt(mean(yf^2)+eps) ----------------
__global__ __launch_bounds__(256) void k4_norm(const float* __restrict__ part,
                                               const float* __restrict__ ssq_part,
                                               float* __restrict__ out){
  const int b = blockIdx.y;
  const int tid = threadIdx.x;
  __shared__ float w4[4];
  __shared__ float sc;
  float v = (tid < NH) ? ssq_part[b * NH + tid] : 0.f;
  #pragma unroll
  for (int m = 32; m; m >>= 1) v += __shfl_xor(v, m);
  const int wid = tid >> 6, lane = tid & 63;
  if (lane == 0) w4[wid] = v;
  __syncthreads();
  if (tid == 0){
    float total = w4[0] + w4[1] + w4[2] + w4[3];
    sc = rsqrtf(total / (float)INTER + EPS_);
  }
  __syncthreads();
  const int j = blockIdx.x * 256 + tid;
  const size_t idx = (size_t)b * 2560 + j;
  const size_t plane = (size_t)NBATCH * 2560;
  float s = part[idx] + part[plane + idx] + part[2*plane + idx] + part[3*plane + idx];
  out[idx] = sc * s;
}

extern "C" void kernel_launch(void* const* d_in, const int* in_sizes, int n_in,
                              void* d_out, int out_size, void* d_ws, size_t ws_size,
                              hipStream_t stream){
  const float* x_in       = (const float*)d_in[0];
  const float* conv_state = (const float*)d_in[1];
  const float* ssm_state  = (const float*)d_in[2];
  const float* in_proj_w  = (const float*)d_in[3];
  const float* conv_w     = (const float*)d_in[4];
  const float* conv_b     = (const float*)d_in[5];
  const float* dt_bias    = (const float*)d_in[6];
  const float* A_log      = (const float*)d_in[7];
  const float* Dp         = (const float*)d_in[8];
  const float* norm_w     = (const float*)d_in[9];
  const float* out_proj_w = (const float*)d_in[10];
  float* out = (float*)d_out;

  char* ws = (char*)d_ws;
  unsigned short* Xb   = (unsigned short*)(ws);             // 327,680 B
  float* dt_part       = (float*)(ws + 327680);             // 163,840 B
  float* pp            = (float*)(ws + 491520);             // 21,659,648 B (8 proj planes)
  float* hs_bc         = (float*)(ws + 22151168);           // 1,376,256 B
  float* dt_sp         = (float*)(ws + 23527424);           // 20,480 B
  float* dAv           = (float*)(ws + 23547904);           // 20,480 B
  float* s_bc          = (float*)(ws + 23568384);           // 256 B
  float* ssq           = (float*)(ws + 23568640);           // 20,480 B
  unsigned short* Yb   = (unsigned short*)(ws + 23589120);  // 655,360 B
  float* part          = (float*)(ws + 24244480);           // 2,621,440 B (4 out planes)

  k_dt<<<dim3(NH, 8), dim3(256), 0, stream>>>(x_in, in_proj_w, dt_part, Xb);
  k1_proj<<<dim3(166, 8), dim3(64), 0, stream>>>(Xb, in_proj_w, pp);
  k2a<<<dim3(14, NBATCH), dim3(256), 0, stream>>>(conv_state, conv_w, conv_b, pp,
                                                  dt_part, dt_bias, A_log,
                                                  hs_bc, dt_sp, dAv, s_bc);
  k2b<<<dim3(NH, NBATCH), dim3(256), 0, stream>>>(ssm_state, hs_bc, pp, dt_sp, dAv,
                                                  s_bc, Dp, norm_w, Yb, ssq);
  k3_out<<<dim3(160, 4), dim3(64), 0, stream>>>(Yb, out_proj_w, part);
  k4_norm<<<dim3(10, NBATCH), dim3(256), 0, stream>>>(part, ssq, out);
}

// Round 16
// 123.342 us; speedup vs baseline: 1.2124x; 1.0335x over previous
//
#include <hip/hip_runtime.h>
#include <stdint.h>

#define HID 2560
#define NH 80
#define PDIM 64
#define NDIM 128
#define INTER 5120
#define CONV_DIM 5376
#define PROJ_DIM 10576
#define NBATCH 64
#define EPS_ 1e-5f

typedef short short8 __attribute__((ext_vector_type(8)));
typedef float f32x4 __attribute__((ext_vector_type(4)));

__device__ __forceinline__ unsigned short f2bf(float f){
  unsigned u = __builtin_bit_cast(unsigned, f);
  u += 0x7FFFu + ((u >> 16) & 1u);
  return (unsigned short)(u >> 16);
}
__device__ __forceinline__ float silu_(float x){ return x / (1.f + __expf(-x)); }

// ---------------- K_dt: exact f32 dt partials + X->bf16 conversion ----------------
__global__ __launch_bounds__(256) void k_dt(const float* __restrict__ X,
                                            const float* __restrict__ W,
                                            float* __restrict__ dt_part,
                                            unsigned short* __restrict__ Xb){
  const int h = blockIdx.x, ks = blockIdx.y;
  const int tid = threadIdx.x, wid = tid >> 6, lane = tid & 63;
  const float* wr = W + (size_t)(INTER + CONV_DIM + h) * HID + ks * 320;
  float w[5];
  #pragma unroll
  for (int i = 0; i < 5; ++i) w[i] = wr[lane + i * 64];
  #pragma unroll
  for (int bi = 0; bi < 16; ++bi){
    const int b = wid * 16 + bi;
    const float* xr = X + (size_t)b * HID + ks * 320;
    float x[5];
    float acc = 0.f;
    #pragma unroll
    for (int i = 0; i < 5; ++i){ x[i] = xr[lane + i * 64]; acc += x[i] * w[i]; }
    if (h == 0){
      #pragma unroll
      for (int i = 0; i < 5; ++i)
        Xb[(size_t)b * HID + ks * 320 + lane + i * 64] = f2bf(x[i]);
    }
    #pragma unroll
    for (int m = 32; m; m >>= 1) acc += __shfl_xor(acc, m);
    if (lane == 0) dt_part[(ks * NBATCH + b) * NH + h] = acc;
  }
}

// ---------------- K1: proj partials, N-tile 64/wave (A shared x4), K-split 8 ----------------
__global__ __launch_bounds__(64, 1) void k1_proj(const unsigned short* __restrict__ Xb,
                                                 const float* __restrict__ W,
                                                 float* __restrict__ pp){
  const int lane = threadIdx.x;
  const int lr = lane & 15, lg = lane >> 4;
  const int n0 = blockIdx.x * 64;
  const int ks = blockIdx.y;
  const int kb = ks * 320;
  const short* ap = (const short*)Xb + (size_t)lr * HID + kb + lg * 8;
  const float* bp0; const float* bp1; const float* bp2; const float* bp3;
  {
    int r0 = n0;          if (r0 > PROJ_DIM - 16) r0 = PROJ_DIM - 16;
    int r1 = n0 + 16;     if (r1 > PROJ_DIM - 16) r1 = PROJ_DIM - 16;
    int r2 = n0 + 32;     if (r2 > PROJ_DIM - 16) r2 = PROJ_DIM - 16;
    int r3 = n0 + 48;     if (r3 > PROJ_DIM - 16) r3 = PROJ_DIM - 16;
    bp0 = W + (size_t)(r0 + lr) * HID + kb + lg * 8;
    bp1 = W + (size_t)(r1 + lr) * HID + kb + lg * 8;
    bp2 = W + (size_t)(r2 + lr) * HID + kb + lg * 8;
    bp3 = W + (size_t)(r3 + lr) * HID + kb + lg * 8;
  }
  f32x4 acc0[4], acc1[4], acc2[4], acc3[4];
  #pragma unroll
  for (int mt = 0; mt < 4; ++mt){
    acc0[mt] = (f32x4){0,0,0,0}; acc1[mt] = (f32x4){0,0,0,0};
    acc2[mt] = (f32x4){0,0,0,0}; acc3[mt] = (f32x4){0,0,0,0};
  }
  short8 A0[2], A1[2], A2[2], A3[2];
  float4 Bv0[2][2], Bv1[2][2], Bv2[2][2], Bv3[2][2];
  A0[0] = *(const short8*)(ap);
  A1[0] = *(const short8*)(ap + 16 * HID);
  A2[0] = *(const short8*)(ap + 32 * HID);
  A3[0] = *(const short8*)(ap + 48 * HID);
  Bv0[0][0] = *(const float4*)(bp0); Bv0[0][1] = *(const float4*)(bp0 + 4);
  Bv1[0][0] = *(const float4*)(bp1); Bv1[0][1] = *(const float4*)(bp1 + 4);
  Bv2[0][0] = *(const float4*)(bp2); Bv2[0][1] = *(const float4*)(bp2 + 4);
  Bv3[0][0] = *(const float4*)(bp3); Bv3[0][1] = *(const float4*)(bp3 + 4);
  #pragma unroll
  for (int s = 0; s < 10; ++s){
    const int p = s & 1;
    if (s + 1 < 10){
      const int k = (s + 1) * 32, q = p ^ 1;
      A0[q] = *(const short8*)(ap + k);
      A1[q] = *(const short8*)(ap + 16 * HID + k);
      A2[q] = *(const short8*)(ap + 32 * HID + k);
      A3[q] = *(const short8*)(ap + 48 * HID + k);
      Bv0[q][0] = *(const float4*)(bp0 + k); Bv0[q][1] = *(const float4*)(bp0 + k + 4);
      Bv1[q][0] = *(const float4*)(bp1 + k); Bv1[q][1] = *(const float4*)(bp1 + k + 4);
      Bv2[q][0] = *(const float4*)(bp2 + k); Bv2[q][1] = *(const float4*)(bp2 + k + 4);
      Bv3[q][0] = *(const float4*)(bp3 + k); Bv3[q][1] = *(const float4*)(bp3 + k + 4);
    }
    short8 bb0, bb1, bb2, bb3;
    bb0[0]=(short)f2bf(Bv0[p][0].x); bb0[1]=(short)f2bf(Bv0[p][0].y);
    bb0[2]=(short)f2bf(Bv0[p][0].z); bb0[3]=(short)f2bf(Bv0[p][0].w);
    bb0[4]=(short)f2bf(Bv0[p][1].x); bb0[5]=(short)f2bf(Bv0[p][1].y);
    bb0[6]=(short)f2bf(Bv0[p][1].z); bb0[7]=(short)f2bf(Bv0[p][1].w);
    bb1[0]=(short)f2bf(Bv1[p][0].x); bb1[1]=(short)f2bf(Bv1[p][0].y);
    bb1[2]=(short)f2bf(Bv1[p][0].z); bb1[3]=(short)f2bf(Bv1[p][0].w);
    bb1[4]=(short)f2bf(Bv1[p][1].x); bb1[5]=(short)f2bf(Bv1[p][1].y);
    bb1[6]=(short)f2bf(Bv1[p][1].z); bb1[7]=(short)f2bf(Bv1[p][1].w);
    bb2[0]=(short)f2bf(Bv2[p][0].x); bb2[1]=(short)f2bf(Bv2[p][0].y);
    bb2[2]=(short)f2bf(Bv2[p][0].z); bb2[3]=(short)f2bf(Bv2[p][0].w);
    bb2[4]=(short)f2bf(Bv2[p][1].x); bb2[5]=(short)f2bf(Bv2[p][1].y);
    bb2[6]=(short)f2bf(Bv2[p][1].z); bb2[7]=(short)f2bf(Bv2[p][1].w);
    bb3[0]=(short)f2bf(Bv3[p][0].x); bb3[1]=(short)f2bf(Bv3[p][0].y);
    bb3[2]=(short)f2bf(Bv3[p][0].z); bb3[3]=(short)f2bf(Bv3[p][0].w);
    bb3[4]=(short)f2bf(Bv3[p][1].x); bb3[5]=(short)f2bf(Bv3[p][1].y);
    bb3[6]=(short)f2bf(Bv3[p][1].z); bb3[7]=(short)f2bf(Bv3[p][1].w);
    acc0[0] = __builtin_amdgcn_mfma_f32_16x16x32_bf16(A0[p], bb0, acc0[0], 0, 0, 0);
    acc0[1] = __builtin_amdgcn_mfma_f32_16x16x32_bf16(A1[p], bb0, acc0[1], 0, 0, 0);
    acc0[2] = __builtin_amdgcn_mfma_f32_16x16x32_bf16(A2[p], bb0, acc0[2], 0, 0, 0);
    acc0[3] = __builtin_amdgcn_mfma_f32_16x16x32_bf16(A3[p], bb0, acc0[3], 0, 0, 0);
    acc1[0] = __builtin_amdgcn_mfma_f32_16x16x32_bf16(A0[p], bb1, acc1[0], 0, 0, 0);
    acc1[1] = __builtin_amdgcn_mfma_f32_16x16x32_bf16(A1[p], bb1, acc1[1], 0, 0, 0);
    acc1[2] = __builtin_amdgcn_mfma_f32_16x16x32_bf16(A2[p], bb1, acc1[2], 0, 0, 0);
    acc1[3] = __builtin_amdgcn_mfma_f32_16x16x32_bf16(A3[p], bb1, acc1[3], 0, 0, 0);
    acc2[0] = __builtin_amdgcn_mfma_f32_16x16x32_bf16(A0[p], bb2, acc2[0], 0, 0, 0);
    acc2[1] = __builtin_amdgcn_mfma_f32_16x16x32_bf16(A1[p], bb2, acc2[1], 0, 0, 0);
    acc2[2] = __builtin_amdgcn_mfma_f32_16x16x32_bf16(A2[p], bb2, acc2[2], 0, 0, 0);
    acc2[3] = __builtin_amdgcn_mfma_f32_16x16x32_bf16(A3[p], bb2, acc2[3], 0, 0, 0);
    acc3[0] = __builtin_amdgcn_mfma_f32_16x16x32_bf16(A0[p], bb3, acc3[0], 0, 0, 0);
    acc3[1] = __builtin_amdgcn_mfma_f32_16x16x32_bf16(A1[p], bb3, acc3[1], 0, 0, 0);
    acc3[2] = __builtin_amdgcn_mfma_f32_16x16x32_bf16(A2[p], bb3, acc3[2], 0, 0, 0);
    acc3[3] = __builtin_amdgcn_mfma_f32_16x16x32_bf16(A3[p], bb3, acc3[3], 0, 0, 0);
  }
  float* plane = pp + (size_t)ks * NBATCH * PROJ_DIM;
  #pragma unroll
  for (int mt = 0; mt < 4; ++mt){
    #pragma unroll
    for (int r = 0; r < 4; ++r){
      const int m = mt * 16 + lg * 4 + r;
      float* pm = plane + (size_t)m * PROJ_DIM;
      if (n0      < PROJ_DIM) pm[n0      + lr] = acc0[mt][r];
      if (n0 + 16 < PROJ_DIM) pm[n0 + 16 + lr] = acc1[mt][r];
      if (n0 + 32 < PROJ_DIM) pm[n0 + 32 + lr] = acc2[mt][r];
      if (n0 + 48 < PROJ_DIM) pm[n0 + 48 + lr] = acc3[mt][r];
    }
  }
}

// ---------------- K2a: conv+silu (pp 8-plane sum); dt finalize; B·C ----------------
__global__ __launch_bounds__(256) void k2a(const float* __restrict__ cs,
                                           const float* __restrict__ cw,
                                           const float* __restrict__ cb,
                                           const float* __restrict__ pp,
                                           const float* __restrict__ dt_part,
                                           const float* __restrict__ dt_bias,
                                           const float* __restrict__ A_log,
                                           float* __restrict__ hs_bc,
                                           float* __restrict__ dt_sp,
                                           float* __restrict__ dAv,
                                           float* __restrict__ s_bc){
  const int b = blockIdx.y;
  const int c0 = blockIdx.x * 384;
  const int tid = threadIdx.x;
  const size_t plane = (size_t)NBATCH * PROJ_DIM;
  __shared__ float bc[384];
  for (int i = tid; i < 384; i += 256){
    const int c = c0 + i;
    float4 s4 = *(const float4*)(cs + ((size_t)b * CONV_DIM + c) * 4);
    float4 w4 = *(const float4*)(cw + (size_t)c * 4);
    const size_t pidx = (size_t)b * PROJ_DIM + INTER + c;
    float hbc = 0.f;
    #pragma unroll
    for (int ks = 0; ks < 8; ++ks) hbc += pp[(size_t)ks * plane + pidx];
    float x = s4.y * w4.x + s4.z * w4.y + s4.w * w4.z + hbc * w4.w + cb[c];
    float v = silu_(x);
    hs_bc[(size_t)b * CONV_DIM + c] = v;
    if (blockIdx.x == 13) bc[i] = v;
  }
  if (blockIdx.x == 0 && tid < NH){
    float acc = dt_bias[tid];
    #pragma unroll
    for (int ks = 0; ks < 8; ++ks) acc += dt_part[(ks * NBATCH + b) * NH + tid];
    float sp = acc > 15.f ? acc : log1pf(__expf(acc));
    sp = fminf(fmaxf(sp, 0.f), 100.f);
    dt_sp[b * NH + tid] = sp;
    dAv[b * NH + tid] = __expf(-sp * __expf(A_log[tid]));
  }
  if (blockIdx.x == 13){
    __syncthreads();
    if (tid < 64){
      float p = bc[128 + tid] * bc[256 + tid] + bc[192 + tid] * bc[320 + tid];
      #pragma unroll
      for (int m = 32; m; m >>= 1) p += __shfl_xor(p, m);
      if (tid == 0) s_bc[b] = p;
    }
  }
}

// ---------------- K2b: SSM step, gate (pp 8-plane sum), yf + sumsq partials ----------------
__global__ __launch_bounds__(256) void k2b(const float* __restrict__ ssm,
                                           const float* __restrict__ hs_bc,
                                           const float* __restrict__ pp,
                                           const float* __restrict__ dt_sp,
                                           const float* __restrict__ dAv,
                                           const float* __restrict__ s_bc,
                                           const float* __restrict__ Dp,
                                           const float* __restrict__ norm_w,
                                           unsigned short* __restrict__ yfb,
                                           float* __restrict__ ssq_part){
  const int h = blockIdx.x, b = blockIdx.y;
  const int tid = threadIdx.x;
  const int wid = tid >> 6, lane = tid & 63;
  const int lr = lane & 15, lg = lane >> 4;
  const float dA_s = dAv[b * NH + h];
  const float coef = dt_sp[b * NH + h] * s_bc[b] + Dp[h];
  const size_t plane = (size_t)NBATCH * PROJ_DIM;
  const float* Cb = hs_bc + (size_t)b * CONV_DIM + INTER + NDIM;
  float4 c0 = *(const float4*)(Cb + lr * 8);
  float4 c1 = *(const float4*)(Cb + lr * 8 + 4);
  const float* srow = ssm + ((size_t)b * NH + h) * PDIM * NDIM;
  float ssq = 0.f;
  __shared__ float ssql[4];
  #pragma unroll
  for (int r = 0; r < 4; ++r){
    const int p = wid * 16 + r * 4 + lg;
    const float* sp_ = srow + (size_t)p * NDIM + lr * 8;
    float4 v0 = *(const float4*)(sp_);
    float4 v1 = *(const float4*)(sp_ + 4);
    float dot = v0.x*c0.x + v0.y*c0.y + v0.z*c0.z + v0.w*c0.w
              + v1.x*c1.x + v1.y*c1.y + v1.z*c1.z + v1.w*c1.w;
    dot += __shfl_xor(dot, 1); dot += __shfl_xor(dot, 2);
    dot += __shfl_xor(dot, 4); dot += __shfl_xor(dot, 8);
    if (lr == 0){
      const int hp = h * PDIM + p;
      float hs = hs_bc[(size_t)b * CONV_DIM + hp];
      float y = dA_s * dot + hs * coef;
      const size_t gi = (size_t)b * PROJ_DIM + hp;
      float g = 0.f;
      #pragma unroll
      for (int ks = 0; ks < 8; ++ks) g += pp[(size_t)ks * plane + gi];
      float yf = y * silu_(g) * norm_w[hp];
      yfb[(size_t)b * INTER + hp] = f2bf(yf);
      ssq += yf * yf;
    }
  }
  #pragma unroll
  for (int m = 32; m; m >>= 1) ssq += __shfl_xor(ssq, m);
  if (lane == 0) ssql[wid] = ssq;
  __syncthreads();
  if (tid == 0) ssq_part[b * NH + h] = ssql[0] + ssql[1] + ssql[2] + ssql[3];
}

// ---------------- K3: out partials, N-tile 32/wave (A shared x2), K-split 16, 2-stage ring ----------------
// grid (80,16) = 1280 single-wave blocks (~5 waves/CU), 10 k-steps. No tail (80*32=2560).
__global__ __launch_bounds__(64, 1) void k3_out(const unsigned short* __restrict__ Yb,
                                                const float* __restrict__ W,
                                                float* __restrict__ part){
  const int lane = threadIdx.x;
  const int lr = lane & 15, lg = lane >> 4;
  const int n0 = blockIdx.x * 32;
  const int ks = blockIdx.y;
  const int kb = ks * 320;
  const short* ap = (const short*)Yb + (size_t)lr * INTER + kb + lg * 8;
  const float* bp0 = W + (size_t)(n0      + lr) * INTER + kb + lg * 8;
  const float* bp1 = W + (size_t)(n0 + 16 + lr) * INTER + kb + lg * 8;
  f32x4 acc0[4], acc1[4];
  #pragma unroll
  for (int mt = 0; mt < 4; ++mt){
    acc0[mt] = (f32x4){0,0,0,0}; acc1[mt] = (f32x4){0,0,0,0};
  }
  short8 A0[2], A1[2], A2[2], A3[2];
  float4 Bv0[2][2], Bv1[2][2];
  A0[0] = *(const short8*)(ap);
  A1[0] = *(const short8*)(ap + 16 * INTER);
  A2[0] = *(const short8*)(ap + 32 * INTER);
  A3[0] = *(const short8*)(ap + 48 * INTER);
  Bv0[0][0] = *(const float4*)(bp0); Bv0[0][1] = *(const float4*)(bp0 + 4);
  Bv1[0][0] = *(const float4*)(bp1); Bv1[0][1] = *(const float4*)(bp1 + 4);
  #pragma unroll
  for (int s = 0; s < 10; ++s){
    const int p = s & 1;
    if (s + 1 < 10){
      const int k = (s + 1) * 32, q = p ^ 1;
      A0[q] = *(const short8*)(ap + k);
      A1[q] = *(const short8*)(ap + 16 * INTER + k);
      A2[q] = *(const short8*)(ap + 32 * INTER + k);
      A3[q] = *(const short8*)(ap + 48 * INTER + k);
      Bv0[q][0] = *(const float4*)(bp0 + k); Bv0[q][1] = *(const float4*)(bp0 + k + 4);
      Bv1[q][0] = *(const float4*)(bp1 + k); Bv1[q][1] = *(const float4*)(bp1 + k + 4);
    }
    short8 bb0, bb1;
    bb0[0]=(short)f2bf(Bv0[p][0].x); bb0[1]=(short)f2bf(Bv0[p][0].y);
    bb0[2]=(short)f2bf(Bv0[p][0].z); bb0[3]=(short)f2bf(Bv0[p][0].w);
    bb0[4]=(short)f2bf(Bv0[p][1].x); bb0[5]=(short)f2bf(Bv0[p][1].y);
    bb0[6]=(short)f2bf(Bv0[p][1].z); bb0[7]=(short)f2bf(Bv0[p][1].w);
    bb1[0]=(short)f2bf(Bv1[p][0].x); bb1[1]=(short)f2bf(Bv1[p][0].y);
    bb1[2]=(short)f2bf(Bv1[p][0].z); bb1[3]=(short)f2bf(Bv1[p][0].w);
    bb1[4]=(short)f2bf(Bv1[p][1].x); bb1[5]=(short)f2bf(Bv1[p][1].y);
    bb1[6]=(short)f2bf(Bv1[p][1].z); bb1[7]=(short)f2bf(Bv1[p][1].w);
    acc0[0] = __builtin_amdgcn_mfma_f32_16x16x32_bf16(A0[p], bb0, acc0[0], 0, 0, 0);
    acc0[1] = __builtin_amdgcn_mfma_f32_16x16x32_bf16(A1[p], bb0, acc0[1], 0, 0, 0);
    acc0[2] = __builtin_amdgcn_mfma_f32_16x16x32_bf16(A2[p], bb0, acc0[2], 0, 0, 0);
    acc0[3] = __builtin_amdgcn_mfma_f32_16x16x32_bf16(A3[p], bb0, acc0[3], 0, 0, 0);
    acc1[0] = __builtin_amdgcn_mfma_f32_16x16x32_bf16(A0[p], bb1, acc1[0], 0, 0, 0);
    acc1[1] = __builtin_amdgcn_mfma_f32_16x16x32_bf16(A1[p], bb1, acc1[1], 0, 0, 0);
    acc1[2] = __builtin_amdgcn_mfma_f32_16x16x32_bf16(A2[p], bb1, acc1[2], 0, 0, 0);
    acc1[3] = __builtin_amdgcn_mfma_f32_16x16x32_bf16(A3[p], bb1, acc1[3], 0, 0, 0);
  }
  float* pt = part + (size_t)ks * NBATCH * 2560;
  #pragma unroll
  for (int mt = 0; mt < 4; ++mt){
    #pragma unroll
    for (int r = 0; r < 4; ++r){
      const int m = mt * 16 + lg * 4 + r;
      float* pm = pt + (size_t)m * 2560;
      pm[n0      + lr] = acc0[mt][r];
      pm[n0 + 16 + lr] = acc1[mt][r];
    }
  }
}

// ---------------- K4: reduce 16 K-partials, apply rsqrt(mean(yf^2)+eps) ----------------
__global__ __launch_bounds__(256) void k4_norm(const float* __restrict__ part,
                                               const float* __restrict__ ssq_part,
                                               float* __restrict__ out){
  const int b = blockIdx.y;
  const int tid = threadIdx.x;
  __shared__ float w4[4];
  __shared__ float sc;
  float v = (tid < NH) ? ssq_part[b * NH + tid] : 0.f;
  #pragma unroll
  for (int m = 32; m; m >>= 1) v += __shfl_xor(v, m);
  const int wid = tid >> 6, lane = tid & 63;
  if (lane == 0) w4[wid] = v;
  __syncthreads();
  if (tid == 0){
    float total = w4[0] + w4[1] + w4[2] + w4[3];
    sc = rsqrtf(total / (float)INTER + EPS_);
  }
  __syncthreads();
  const int j = blockIdx.x * 256 + tid;
  const size_t idx = (size_t)b * 2560 + j;
  const size_t plane = (size_t)NBATCH * 2560;
  float s = 0.f;
  #pragma unroll
  for (int ks = 0; ks < 16; ++ks) s += part[(size_t)ks * plane + idx];
  out[idx] = sc * s;
}

extern "C" void kernel_launch(void* const* d_in, const int* in_sizes, int n_in,
                              void* d_out, int out_size, void* d_ws, size_t ws_size,
                              hipStream_t stream){
  const float* x_in       = (const float*)d_in[0];
  const float* conv_state = (const float*)d_in[1];
  const float* ssm_state  = (const float*)d_in[2];
  const float* in_proj_w  = (const float*)d_in[3];
  const float* conv_w     = (const float*)d_in[4];
  const float* conv_b     = (const float*)d_in[5];
  const float* dt_bias    = (const float*)d_in[6];
  const float* A_log      = (const float*)d_in[7];
  const float* Dp         = (const float*)d_in[8];
  const float* norm_w     = (const float*)d_in[9];
  const float* out_proj_w = (const float*)d_in[10];
  float* out = (float*)d_out;

  char* ws = (char*)d_ws;
  unsigned short* Xb   = (unsigned short*)(ws);             // 327,680 B
  float* dt_part       = (float*)(ws + 327680);             // 163,840 B
  float* pp            = (float*)(ws + 491520);             // 21,659,648 B (8 proj planes)
  float* hs_bc         = (float*)(ws + 22151168);           // 1,376,256 B
  float* dt_sp         = (float*)(ws + 23527424);           // 20,480 B
  float* dAv           = (float*)(ws + 23547904);           // 20,480 B
  float* s_bc          = (float*)(ws + 23568384);           // 256 B
  float* ssq           = (float*)(ws + 23568640);           // 20,480 B
  unsigned short* Yb   = (unsigned short*)(ws + 23589120);  // 655,360 B
  float* part          = (float*)(ws + 24244480);           // 10,485,760 B (16 out planes)

  k_dt<<<dim3(NH, 8), dim3(256), 0, stream>>>(x_in, in_proj_w, dt_part, Xb);
  k1_proj<<<dim3(166, 8), dim3(64), 0, stream>>>(Xb, in_proj_w, pp);
  k2a<<<dim3(14, NBATCH), dim3(256), 0, stream>>>(conv_state, conv_w, conv_b, pp,
                                                  dt_part, dt_bias, A_log,
                                                  hs_bc, dt_sp, dAv, s_bc);
  k2b<<<dim3(NH, NBATCH), dim3(256), 0, stream>>>(ssm_state, hs_bc, pp, dt_sp, dAv,
                                                  s_bc, Dp, norm_w, Yb, ssq);
  k3_out<<<dim3(80, 16), dim3(64), 0, stream>>>(Yb, out_proj_w, part);
  k4_norm<<<dim3(10, NBATCH), dim3(256), 0, stream>>>(part, ssq, out);
}